// Round 1
// baseline (6263.576 us; speedup 1.0000x reference)
//
#include <hip/hip_runtime.h>

// Problem constants (shapes fixed by the reference)
#define F_IN 256
#define HID  128
#define SSUB 50

// ---------------- degree / norm ----------------

__global__ void k_init_deg(float* __restrict__ deg, int N) {
    int i = blockIdx.x * blockDim.x + threadIdx.x;
    if (i < N) deg[i] = 1.0f;  // self-loop contributes 1
}

__global__ void k_count_deg(const int* __restrict__ dst, float* __restrict__ deg, int E) {
    int e = blockIdx.x * blockDim.x + threadIdx.x;
    if (e < E) atomicAdd(&deg[dst[e]], 1.0f);
}

__global__ void k_deg_to_dinv(float* __restrict__ deg, int N) {
    int i = blockIdx.x * blockDim.x + threadIdx.x;
    if (i < N) deg[i] = rsqrtf(deg[i]);  // deg >= 1 always (self loop)
}

// ---------------- GEMM1: h0 = x @ W1  (K=256) ----------------
// one block (128 threads) per node row; x row staged in LDS; W1 column-read coalesced
__global__ void k_gemm1(const float* __restrict__ x, const float* __restrict__ W1,
                        float* __restrict__ h0, int N) {
    __shared__ float xs[F_IN];
    int n = blockIdx.x;
    int j = threadIdx.x;
    xs[j]       = x[(size_t)n * F_IN + j];
    xs[j + 128] = x[(size_t)n * F_IN + j + 128];
    __syncthreads();
    float acc = 0.f;
#pragma unroll 8
    for (int k = 0; k < F_IN; ++k)
        acc += xs[k] * W1[(size_t)k * HID + j];
    h0[(size_t)n * HID + j] = acc;
}

// ---------------- GEMM2: h1 = h @ W2  (K=128) ----------------
__global__ void k_gemm2(const float* __restrict__ h, const float* __restrict__ W2,
                        float* __restrict__ h1, int N) {
    __shared__ float hs[HID];
    int n = blockIdx.x;
    int j = threadIdx.x;
    hs[j] = h[(size_t)n * HID + j];
    __syncthreads();
    float acc = 0.f;
#pragma unroll 8
    for (int k = 0; k < HID; ++k)
        acc += hs[k] * W2[(size_t)k * HID + j];
    h1[(size_t)n * HID + j] = acc;
}

// ---------------- self-loop init of the aggregation buffer ----------------
// layer1: agg[n][j] = h0[n][j] * dinv[n]^2          (bias added later w/ relu)
// layer2: agg[n][j] = h1[n][j] * dinv[n]^2 + b2[j]  (bias is additive, fold here)
__global__ void k_self_init(const float* __restrict__ hin, const float* __restrict__ dinv,
                            const float* __restrict__ bias,  // may be null
                            float* __restrict__ agg, int total) {
    int t = blockIdx.x * blockDim.x + threadIdx.x;
    if (t >= total) return;
    int n = t >> 7;           // /HID
    int j = t & (HID - 1);
    float d = dinv[n];
    float v = hin[t] * d * d;
    if (bias) v += bias[j];
    agg[t] = v;
}

// ---------------- edge scatter: agg[dst] += h[src] * dinv[src]*dinv[dst] ----------------
// 32 threads per edge, 4 consecutive floats each (float4 gather, 4 scalar atomics)
__global__ void k_scatter(const int* __restrict__ src, const int* __restrict__ dst,
                          const float* __restrict__ dinv, const float* __restrict__ hin,
                          float* __restrict__ agg, int E) {
    int t = blockIdx.x * blockDim.x + threadIdx.x;
    int e = t >> 5;
    if (e >= E) return;
    int lane = t & 31;
    int s = src[e];
    int d = dst[e];
    float w = dinv[s] * dinv[d];
    const float4* hv = (const float4*)(hin + (size_t)s * HID);
    float4 v = hv[lane];
    float* out = agg + (size_t)d * HID + lane * 4;
    atomicAdd(out + 0, v.x * w);
    atomicAdd(out + 1, v.y * w);
    atomicAdd(out + 2, v.z * w);
    atomicAdd(out + 3, v.w * w);
}

// ---------------- bias + relu (layer 1 epilogue) ----------------
__global__ void k_bias_relu(float* __restrict__ h, const float* __restrict__ b, int total) {
    int t = blockIdx.x * blockDim.x + threadIdx.x;
    if (t >= total) return;
    int j = t & (HID - 1);
    h[t] = fmaxf(h[t] + b[j], 0.f);
}

// ---------------- final: out[g] = emb.reshape(G, S*H)[g] @ Wl + bl ----------------
// one block (128 threads) per output row g; pooled row chunks staged in LDS
__global__ void k_final(const float* __restrict__ emb, const float* __restrict__ Wl,
                        const float* __restrict__ bl, float* __restrict__ out, int G) {
    __shared__ float ps[128];
    int g = blockIdx.x;
    int j = threadIdx.x;
    float acc = bl[j];
    const float* prow = emb + (size_t)g * (SSUB * HID);
    for (int kc = 0; kc < SSUB * HID; kc += 128) {
        __syncthreads();
        ps[j] = prow[kc + j];
        __syncthreads();
#pragma unroll 8
        for (int kk = 0; kk < 128; ++kk)
            acc += ps[kk] * Wl[(size_t)(kc + kk) * HID + j];
    }
    out[(size_t)g * HID + j] = acc;
}

extern "C" void kernel_launch(void* const* d_in, const int* in_sizes, int n_in,
                              void* d_out, int out_size, void* d_ws, size_t ws_size,
                              hipStream_t stream) {
    const float* x  = (const float*)d_in[0];
    const float* W1 = (const float*)d_in[1];
    const float* b1 = (const float*)d_in[2];
    const float* W2 = (const float*)d_in[3];
    const float* b2 = (const float*)d_in[4];
    const float* Wl = (const float*)d_in[5];
    const float* bl = (const float*)d_in[6];
    const int* edge = (const int*)d_in[7];

    const int N = in_sizes[0] / F_IN;       // 50000
    const int E = in_sizes[7] / 2;          // 1600000
    const int G = N / SSUB;                 // 1000
    const int NH = N * HID;

    const int* src = edge;
    const int* dst = edge + E;

    // workspace layout (floats)
    float* ws    = (float*)d_ws;
    float* dinv  = ws;                       // N
    float* h0    = ws + 51200;               // N*H
    float* h     = h0 + (size_t)NH;          // N*H  (agg1 -> relu'd h)
    float* h1    = h  + (size_t)NH;          // N*H

    float* out_final = (float*)d_out;            // G*H
    float* emb       = out_final + (size_t)G * HID;  // N*H (second tuple output)

    // ---- norm ----
    k_init_deg<<<(N + 255) / 256, 256, 0, stream>>>(dinv, N);
    k_count_deg<<<(E + 255) / 256, 256, 0, stream>>>(dst, dinv, E);
    k_deg_to_dinv<<<(N + 255) / 256, 256, 0, stream>>>(dinv, N);

    // ---- layer 1 ----
    k_gemm1<<<N, 128, 0, stream>>>(x, W1, h0, N);
    k_self_init<<<(NH + 255) / 256, 256, 0, stream>>>(h0, dinv, nullptr, h, NH);
    {
        long long tot = (long long)E * 32;
        k_scatter<<<(int)((tot + 255) / 256), 256, 0, stream>>>(src, dst, dinv, h0, h, E);
    }
    k_bias_relu<<<(NH + 255) / 256, 256, 0, stream>>>(h, b1, NH);

    // ---- layer 2 ----
    k_gemm2<<<N, 128, 0, stream>>>(h, W2, h1, N);
    k_self_init<<<(NH + 255) / 256, 256, 0, stream>>>(h1, dinv, b2, emb, NH);
    {
        long long tot = (long long)E * 32;
        k_scatter<<<(int)((tot + 255) / 256), 256, 0, stream>>>(src, dst, dinv, h1, emb, E);
    }

    // ---- final linear over pooled rows ----
    k_final<<<G, 128, 0, stream>>>(emb, Wl, bl, out_final, G);
}

// Round 2
// 1426.786 us; speedup vs baseline: 4.3900x; 4.3900x over previous
//
#include <hip/hip_runtime.h>

#define F_IN 256
#define HID  128
#define SSUB 50

// ---------------- CSR build ----------------

__global__ void k_zero_int(int* __restrict__ p, int n) {
    int i = blockIdx.x * blockDim.x + threadIdx.x;
    if (i < n) p[i] = 0;
}

__global__ void k_hist(const int* __restrict__ dst, int* __restrict__ cnt, int E) {
    int e = blockIdx.x * blockDim.x + threadIdx.x;
    if (e < E) atomicAdd(&cnt[dst[e]], 1);
}

// single-block exclusive scan over cnt[0..N) -> row_ptr, cursor; also dinv = rsqrt(cnt+1)
__global__ void k_scan(const int* __restrict__ cnt, int* __restrict__ row_ptr,
                       int* __restrict__ cursor, float* __restrict__ dinv, int N) {
    __shared__ int buf[256];
    __shared__ int carry_s;
    int tid = threadIdx.x;
    if (tid == 0) carry_s = 0;
    __syncthreads();
    for (int base = 0; base < N; base += 256) {
        int i = base + tid;
        int v = (i < N) ? cnt[i] : 0;
        buf[tid] = v;
        __syncthreads();
        for (int off = 1; off < 256; off <<= 1) {
            int t = (tid >= off) ? buf[tid - off] : 0;
            __syncthreads();
            buf[tid] += t;
            __syncthreads();
        }
        int carry = carry_s;
        int excl = carry + buf[tid] - v;
        if (i < N) {
            row_ptr[i] = excl;
            cursor[i] = excl;
            dinv[i] = rsqrtf((float)(v + 1));   // +1 self loop
        }
        __syncthreads();
        if (tid == 255) carry_s = carry + buf[255];
        __syncthreads();
    }
    if (tid == 0) row_ptr[N] = carry_s;
}

__global__ void k_fill_csr(const int* __restrict__ src, const int* __restrict__ dst,
                           const float* __restrict__ dinv, int* __restrict__ cursor,
                           int* __restrict__ csr_src, float* __restrict__ csr_w, int E) {
    int e = blockIdx.x * blockDim.x + threadIdx.x;
    if (e >= E) return;
    int s = src[e];
    int d = dst[e];
    int pos = atomicAdd(&cursor[d], 1);
    csr_src[pos] = s;
    csr_w[pos] = dinv[s] * dinv[d];
}

// ---------------- GEMM1: h0 = x @ W1  (K=256) ----------------
__global__ void k_gemm1(const float* __restrict__ x, const float* __restrict__ W1,
                        float* __restrict__ h0, int N) {
    __shared__ float xs[F_IN];
    int n = blockIdx.x;
    int j = threadIdx.x;
    xs[j]       = x[(size_t)n * F_IN + j];
    xs[j + 128] = x[(size_t)n * F_IN + j + 128];
    __syncthreads();
    float acc = 0.f;
#pragma unroll 8
    for (int k = 0; k < F_IN; ++k)
        acc += xs[k] * W1[(size_t)k * HID + j];
    h0[(size_t)n * HID + j] = acc;
}

// ---------------- GEMM2: h1 = h @ W2  (K=128) ----------------
__global__ void k_gemm2(const float* __restrict__ h, const float* __restrict__ W2,
                        float* __restrict__ h1, int N) {
    __shared__ float hs[HID];
    int n = blockIdx.x;
    int j = threadIdx.x;
    hs[j] = h[(size_t)n * HID + j];
    __syncthreads();
    float acc = 0.f;
#pragma unroll 8
    for (int k = 0; k < HID; ++k)
        acc += hs[k] * W2[(size_t)k * HID + j];
    h1[(size_t)n * HID + j] = acc;
}

// ---------------- CSR aggregation, fused self-loop + bias (+relu) ----------------
// one block (128 threads) per dst node; j = feature
__global__ void k_agg(const float* __restrict__ hin, const int* __restrict__ row_ptr,
                      const int* __restrict__ csr_src, const float* __restrict__ csr_w,
                      const float* __restrict__ dinv, const float* __restrict__ bias,
                      float* __restrict__ out, int relu) {
    int n = blockIdx.x;
    int j = threadIdx.x;
    int beg = row_ptr[n];
    int end = row_ptr[n + 1];
    float d = dinv[n];
    float acc = hin[(size_t)n * HID + j] * d * d;   // self loop
    int k = beg;
    for (; k + 3 < end; k += 4) {
        int s0 = csr_src[k + 0], s1 = csr_src[k + 1];
        int s2 = csr_src[k + 2], s3 = csr_src[k + 3];
        float w0 = csr_w[k + 0], w1 = csr_w[k + 1];
        float w2 = csr_w[k + 2], w3 = csr_w[k + 3];
        float v0 = hin[(size_t)s0 * HID + j];
        float v1 = hin[(size_t)s1 * HID + j];
        float v2 = hin[(size_t)s2 * HID + j];
        float v3 = hin[(size_t)s3 * HID + j];
        acc += v0 * w0 + v1 * w1 + v2 * w2 + v3 * w3;
    }
    for (; k < end; ++k) {
        int s = csr_src[k];
        acc += hin[(size_t)s * HID + j] * csr_w[k];
    }
    acc += bias[j];
    if (relu) acc = fmaxf(acc, 0.f);
    out[(size_t)n * HID + j] = acc;
}

// ---------------- final: out[g] = emb.reshape(G, S*H)[g] @ Wl + bl ----------------
__global__ void k_final(const float* __restrict__ emb, const float* __restrict__ Wl,
                        const float* __restrict__ bl, float* __restrict__ out, int G) {
    __shared__ float ps[128];
    int g = blockIdx.x;
    int j = threadIdx.x;
    float acc = bl[j];
    const float* prow = emb + (size_t)g * (SSUB * HID);
    for (int kc = 0; kc < SSUB * HID; kc += 128) {
        __syncthreads();
        ps[j] = prow[kc + j];
        __syncthreads();
#pragma unroll 8
        for (int kk = 0; kk < 128; ++kk)
            acc += ps[kk] * Wl[(size_t)(kc + kk) * HID + j];
    }
    out[(size_t)g * HID + j] = acc;
}

extern "C" void kernel_launch(void* const* d_in, const int* in_sizes, int n_in,
                              void* d_out, int out_size, void* d_ws, size_t ws_size,
                              hipStream_t stream) {
    const float* x  = (const float*)d_in[0];
    const float* W1 = (const float*)d_in[1];
    const float* b1 = (const float*)d_in[2];
    const float* W2 = (const float*)d_in[3];
    const float* b2 = (const float*)d_in[4];
    const float* Wl = (const float*)d_in[5];
    const float* bl = (const float*)d_in[6];
    const int* edge = (const int*)d_in[7];

    const int N = in_sizes[0] / F_IN;       // 50000
    const int E = in_sizes[7] / 2;          // 1600000
    const int G = N / SSUB;                 // 1000
    const int NH = N * HID;

    const int* src = edge;
    const int* dst = edge + E;

    // workspace layout
    char* ws = (char*)d_ws;
    float* dinv    = (float*)ws;                 ws += (size_t)N * 4;        // N
    int*   cnt     = (int*)ws;                   ws += (size_t)N * 4;
    int*   row_ptr = (int*)ws;                   ws += (size_t)(N + 64) * 4;
    int*   cursor  = (int*)ws;                   ws += (size_t)N * 4;
    int*   csr_src = (int*)ws;                   ws += (size_t)E * 4;
    float* csr_w   = (float*)ws;                 ws += (size_t)E * 4;
    float* h0      = (float*)ws;                 ws += (size_t)NH * 4;       // also reused as h1
    float* h       = (float*)ws;                 ws += (size_t)NH * 4;
    float* h1      = h0;                         // reuse after layer-1 agg

    float* out_final = (float*)d_out;                 // G*H
    float* emb       = out_final + (size_t)G * HID;   // N*H

    // ---- CSR build (also computes dinv) ----
    k_zero_int<<<(N + 255) / 256, 256, 0, stream>>>(cnt, N);
    k_hist<<<(E + 255) / 256, 256, 0, stream>>>(dst, cnt, E);
    k_scan<<<1, 256, 0, stream>>>(cnt, row_ptr, cursor, dinv, N);
    k_fill_csr<<<(E + 255) / 256, 256, 0, stream>>>(src, dst, dinv, cursor, csr_src, csr_w, E);

    // ---- layer 1 ----
    k_gemm1<<<N, 128, 0, stream>>>(x, W1, h0, N);
    k_agg<<<N, 128, 0, stream>>>(h0, row_ptr, csr_src, csr_w, dinv, b1, h, 1);

    // ---- layer 2 ----
    k_gemm2<<<N, 128, 0, stream>>>(h, W2, h1, N);
    k_agg<<<N, 128, 0, stream>>>(h1, row_ptr, csr_src, csr_w, dinv, b2, emb, 0);

    // ---- final linear ----
    k_final<<<G, 128, 0, stream>>>(emb, Wl, bl, out_final, G);
}

// Round 3
// 1058.768 us; speedup vs baseline: 5.9159x; 1.3476x over previous
//
#include <hip/hip_runtime.h>

#define F_IN 256
#define HID  128
#define SSUB 50

// ---------------- CSR build ----------------

__global__ void k_zero_int(int* __restrict__ p, int n) {
    int i = blockIdx.x * blockDim.x + threadIdx.x;
    if (i < n) p[i] = 0;
}

__global__ void k_hist(const int* __restrict__ dst, int* __restrict__ cnt, int E) {
    int e = blockIdx.x * blockDim.x + threadIdx.x;
    if (e < E) atomicAdd(&cnt[dst[e]], 1);
}

// single-block exclusive scan over cnt[0..N) -> row_ptr, cursor; also dinv = rsqrt(cnt+1)
__global__ void k_scan(const int* __restrict__ cnt, int* __restrict__ row_ptr,
                       int* __restrict__ cursor, float* __restrict__ dinv, int N) {
    __shared__ int buf[256];
    __shared__ int carry_s;
    int tid = threadIdx.x;
    if (tid == 0) carry_s = 0;
    __syncthreads();
    for (int base = 0; base < N; base += 256) {
        int i = base + tid;
        int v = (i < N) ? cnt[i] : 0;
        buf[tid] = v;
        __syncthreads();
        for (int off = 1; off < 256; off <<= 1) {
            int t = (tid >= off) ? buf[tid - off] : 0;
            __syncthreads();
            buf[tid] += t;
            __syncthreads();
        }
        int carry = carry_s;
        int excl = carry + buf[tid] - v;
        if (i < N) {
            row_ptr[i] = excl;
            cursor[i] = excl;
            dinv[i] = rsqrtf((float)(v + 1));   // +1 self loop
        }
        __syncthreads();
        if (tid == 255) carry_s = carry + buf[255];
        __syncthreads();
    }
    if (tid == 0) row_ptr[N] = carry_s;
}

__global__ void k_fill_csr(const int* __restrict__ src, const int* __restrict__ dst,
                           const float* __restrict__ dinv, int* __restrict__ cursor,
                           int* __restrict__ csr_src, float* __restrict__ csr_w, int E) {
    int e = blockIdx.x * blockDim.x + threadIdx.x;
    if (e >= E) return;
    int s = src[e];
    int d = dst[e];
    int pos = atomicAdd(&cursor[d], 1);
    csr_src[pos] = s;
    csr_w[pos] = dinv[s] * dinv[d];
}

// ---------------- GEMM1: h0 = x @ W1  (K=256), 8 rows/block ----------------
#define G1R 8
__global__ void k_gemm1(const float* __restrict__ x, const float* __restrict__ W1,
                        float* __restrict__ h0, int N) {
    int n0 = blockIdx.x * G1R;
    int j = threadIdx.x;
    const float* xr = x + (size_t)n0 * F_IN;
    float acc[G1R] = {};
#pragma unroll 4
    for (int k = 0; k < F_IN; ++k) {
        float w = W1[(size_t)k * HID + j];
#pragma unroll
        for (int r = 0; r < G1R; ++r)
            acc[r] += xr[(size_t)r * F_IN + k] * w;
    }
#pragma unroll
    for (int r = 0; r < G1R; ++r)
        h0[(size_t)(n0 + r) * HID + j] = acc[r];
}

// ---------------- GEMM2: h1 = h @ W2  (K=128), 8 rows/block ----------------
__global__ void k_gemm2(const float* __restrict__ h, const float* __restrict__ W2,
                        float* __restrict__ h1, int N) {
    int n0 = blockIdx.x * G1R;
    int j = threadIdx.x;
    const float* hr = h + (size_t)n0 * HID;
    float acc[G1R] = {};
#pragma unroll 4
    for (int k = 0; k < HID; ++k) {
        float w = W2[(size_t)k * HID + j];
#pragma unroll
        for (int r = 0; r < G1R; ++r)
            acc[r] += hr[(size_t)r * HID + k] * w;
    }
#pragma unroll
    for (int r = 0; r < G1R; ++r)
        h1[(size_t)(n0 + r) * HID + j] = acc[r];
}

// ---------------- CSR aggregation, fused self-loop + bias (+relu) ----------------
__global__ void k_agg(const float* __restrict__ hin, const int* __restrict__ row_ptr,
                      const int* __restrict__ csr_src, const float* __restrict__ csr_w,
                      const float* __restrict__ dinv, const float* __restrict__ bias,
                      float* __restrict__ out, int relu) {
    int n = blockIdx.x;
    int j = threadIdx.x;
    int beg = row_ptr[n];
    int end = row_ptr[n + 1];
    float d = dinv[n];
    float acc = hin[(size_t)n * HID + j] * d * d;   // self loop
    int k = beg;
    for (; k + 3 < end; k += 4) {
        int s0 = csr_src[k + 0], s1 = csr_src[k + 1];
        int s2 = csr_src[k + 2], s3 = csr_src[k + 3];
        float w0 = csr_w[k + 0], w1 = csr_w[k + 1];
        float w2 = csr_w[k + 2], w3 = csr_w[k + 3];
        float v0 = hin[(size_t)s0 * HID + j];
        float v1 = hin[(size_t)s1 * HID + j];
        float v2 = hin[(size_t)s2 * HID + j];
        float v3 = hin[(size_t)s3 * HID + j];
        acc += v0 * w0 + v1 * w1 + v2 * w2 + v3 * w3;
    }
    for (; k < end; ++k) {
        int s = csr_src[k];
        acc += hin[(size_t)s * HID + j] * csr_w[k];
    }
    acc += bias[j];
    if (relu) acc = fmaxf(acc, 0.f);
    out[(size_t)n * HID + j] = acc;
}

// ---------------- final linear: out = pooled @ Wl + bl ----------------
// init out with bias, then 8-row × split-K blocks accumulate via atomics
__global__ void k_final_init(const float* __restrict__ bl, float* __restrict__ out, int total) {
    int t = blockIdx.x * blockDim.x + threadIdx.x;
    if (t < total) out[t] = bl[t & (HID - 1)];
}

#define FR  8      // g-rows per block
#define FKC 800    // K-chunk (6400 / 8)
__global__ void k_final(const float* __restrict__ emb, const float* __restrict__ Wl,
                        float* __restrict__ out, int G) {
    int g0 = blockIdx.x * FR;
    int c  = blockIdx.y;
    int j  = threadIdx.x;
    int k0 = c * FKC;
    const float* pr = emb + (size_t)g0 * (SSUB * HID) + k0;
    float acc[FR] = {};
#pragma unroll 4
    for (int k = 0; k < FKC; ++k) {
        float w = Wl[(size_t)(k0 + k) * HID + j];
#pragma unroll
        for (int r = 0; r < FR; ++r)
            acc[r] += pr[(size_t)r * (SSUB * HID) + k] * w;
    }
#pragma unroll
    for (int r = 0; r < FR; ++r)
        atomicAdd(&out[(size_t)(g0 + r) * HID + j], acc[r]);
}

extern "C" void kernel_launch(void* const* d_in, const int* in_sizes, int n_in,
                              void* d_out, int out_size, void* d_ws, size_t ws_size,
                              hipStream_t stream) {
    const float* x  = (const float*)d_in[0];
    const float* W1 = (const float*)d_in[1];
    const float* b1 = (const float*)d_in[2];
    const float* W2 = (const float*)d_in[3];
    const float* b2 = (const float*)d_in[4];
    const float* Wl = (const float*)d_in[5];
    const float* bl = (const float*)d_in[6];
    const int* edge = (const int*)d_in[7];

    const int N = in_sizes[0] / F_IN;       // 50000
    const int E = in_sizes[7] / 2;          // 1600000
    const int G = N / SSUB;                 // 1000
    const int NH = N * HID;

    const int* src = edge;
    const int* dst = edge + E;

    // workspace layout
    char* ws = (char*)d_ws;
    float* dinv    = (float*)ws;                 ws += (size_t)N * 4;
    int*   cnt     = (int*)ws;                   ws += (size_t)N * 4;
    int*   row_ptr = (int*)ws;                   ws += (size_t)(N + 64) * 4;
    int*   cursor  = (int*)ws;                   ws += (size_t)N * 4;
    int*   csr_src = (int*)ws;                   ws += (size_t)E * 4;
    float* csr_w   = (float*)ws;                 ws += (size_t)E * 4;
    float* h0      = (float*)ws;                 ws += (size_t)NH * 4;
    float* h       = (float*)ws;                 ws += (size_t)NH * 4;
    float* h1      = h0;                         // reuse after layer-1 agg

    float* out_final = (float*)d_out;                 // G*H
    float* emb       = out_final + (size_t)G * HID;   // N*H

    // ---- CSR build (also computes dinv) ----
    k_zero_int<<<(N + 255) / 256, 256, 0, stream>>>(cnt, N);
    k_hist<<<(E + 255) / 256, 256, 0, stream>>>(dst, cnt, E);
    k_scan<<<1, 256, 0, stream>>>(cnt, row_ptr, cursor, dinv, N);
    k_fill_csr<<<(E + 255) / 256, 256, 0, stream>>>(src, dst, dinv, cursor, csr_src, csr_w, E);

    // ---- layer 1 ----
    k_gemm1<<<N / G1R, 128, 0, stream>>>(x, W1, h0, N);
    k_agg<<<N, 128, 0, stream>>>(h0, row_ptr, csr_src, csr_w, dinv, b1, h, 1);

    // ---- layer 2 ----
    k_gemm2<<<N / G1R, 128, 0, stream>>>(h, W2, h1, N);
    k_agg<<<N, 128, 0, stream>>>(h1, row_ptr, csr_src, csr_w, dinv, b2, emb, 0);

    // ---- final linear ----
    k_final_init<<<(G * HID + 255) / 256, 256, 0, stream>>>(bl, out_final, G * HID);
    {
        dim3 grid(G / FR, (SSUB * HID) / FKC);
        k_final<<<grid, 128, 0, stream>>>(emb, Wl, out_final, G);
    }
}

// Round 4
// 871.274 us; speedup vs baseline: 7.1890x; 1.2152x over previous
//
#include <hip/hip_runtime.h>

#define F_IN 256
#define HID  128
#define SSUB 50

// ---------------- CSR build ----------------

__global__ void k_zero_int(int* __restrict__ p, int n) {
    int i = blockIdx.x * blockDim.x + threadIdx.x;
    if (i < n) p[i] = 0;
}

__global__ void k_hist(const int* __restrict__ dst, int* __restrict__ cnt, int E) {
    int e = blockIdx.x * blockDim.x + threadIdx.x;
    if (e < E) atomicAdd(&cnt[dst[e]], 1);
}

// ---- hierarchical exclusive scan over cnt[0..N) ----
// phase 1: per-block local exclusive scan (also computes dinv = rsqrt(cnt+1))
__global__ void k_scan_local(const int* __restrict__ cnt, int* __restrict__ row_ptr,
                             float* __restrict__ dinv, int* __restrict__ blk_sum, int N) {
    __shared__ int buf[256];
    int tid = threadIdx.x;
    int i = blockIdx.x * 256 + tid;
    int v = (i < N) ? cnt[i] : 0;
    buf[tid] = v;
    __syncthreads();
    for (int off = 1; off < 256; off <<= 1) {
        int t = (tid >= off) ? buf[tid - off] : 0;
        __syncthreads();
        buf[tid] += t;
        __syncthreads();
    }
    if (i < N) {
        row_ptr[i] = buf[tid] - v;   // local exclusive
        dinv[i] = rsqrtf((float)(v + 1));   // +1 self loop
    }
    if (tid == 255) blk_sum[blockIdx.x] = buf[255];
}

// phase 2: single block scans block sums (nblk <= 256)
__global__ void k_scan_blk(const int* __restrict__ blk_sum, int* __restrict__ blk_off, int nblk) {
    __shared__ int buf[256];
    int tid = threadIdx.x;
    int v = (tid < nblk) ? blk_sum[tid] : 0;
    buf[tid] = v;
    __syncthreads();
    for (int off = 1; off < 256; off <<= 1) {
        int t = (tid >= off) ? buf[tid - off] : 0;
        __syncthreads();
        buf[tid] += t;
        __syncthreads();
    }
    if (tid < nblk) blk_off[tid] = buf[tid] - v;   // exclusive
    if (tid == 255) blk_off[nblk] = buf[255];      // grand total
}

// phase 3: add block offsets; produce row_ptr and cursor
__global__ void k_scan_add(int* __restrict__ row_ptr, int* __restrict__ cursor,
                           const int* __restrict__ blk_off, int N, int nblk) {
    int i = blockIdx.x * 256 + threadIdx.x;
    if (i < N) {
        int val = row_ptr[i] + blk_off[blockIdx.x];
        row_ptr[i] = val;
        cursor[i] = val;
    }
    if (i == 0) row_ptr[N] = blk_off[nblk];
}

__global__ void k_fill_csr(const int* __restrict__ src, const int* __restrict__ dst,
                           const float* __restrict__ dinv, int* __restrict__ cursor,
                           int* __restrict__ csr_src, float* __restrict__ csr_w, int E) {
    int e = blockIdx.x * blockDim.x + threadIdx.x;
    if (e >= E) return;
    int s = src[e];
    int d = dst[e];
    int pos = atomicAdd(&cursor[d], 1);
    csr_src[pos] = s;
    csr_w[pos] = dinv[s] * dinv[d];
}

// ---------------- GEMM1: h0 = x @ W1  (K=256), 8 rows/block ----------------
#define G1R 8
__global__ void k_gemm1(const float* __restrict__ x, const float* __restrict__ W1,
                        float* __restrict__ h0, int N) {
    int n0 = blockIdx.x * G1R;
    int j = threadIdx.x;
    const float* xr = x + (size_t)n0 * F_IN;
    float acc[G1R] = {};
#pragma unroll 4
    for (int k = 0; k < F_IN; ++k) {
        float w = W1[(size_t)k * HID + j];
#pragma unroll
        for (int r = 0; r < G1R; ++r)
            acc[r] += xr[(size_t)r * F_IN + k] * w;
    }
#pragma unroll
    for (int r = 0; r < G1R; ++r)
        h0[(size_t)(n0 + r) * HID + j] = acc[r];
}

// ---------------- GEMM2: h1 = h @ W2  (K=128), 8 rows/block ----------------
__global__ void k_gemm2(const float* __restrict__ h, const float* __restrict__ W2,
                        float* __restrict__ h1, int N) {
    int n0 = blockIdx.x * G1R;
    int j = threadIdx.x;
    const float* hr = h + (size_t)n0 * HID;
    float acc[G1R] = {};
#pragma unroll 4
    for (int k = 0; k < HID; ++k) {
        float w = W2[(size_t)k * HID + j];
#pragma unroll
        for (int r = 0; r < G1R; ++r)
            acc[r] += hr[(size_t)r * HID + k] * w;
    }
#pragma unroll
    for (int r = 0; r < G1R; ++r)
        h1[(size_t)(n0 + r) * HID + j] = acc[r];
}

// ---------------- CSR aggregation, fused self-loop + bias (+relu) ----------------
__global__ void k_agg(const float* __restrict__ hin, const int* __restrict__ row_ptr,
                      const int* __restrict__ csr_src, const float* __restrict__ csr_w,
                      const float* __restrict__ dinv, const float* __restrict__ bias,
                      float* __restrict__ out, int relu) {
    int n = blockIdx.x;
    int j = threadIdx.x;
    int beg = row_ptr[n];
    int end = row_ptr[n + 1];
    float d = dinv[n];
    float acc = hin[(size_t)n * HID + j] * d * d;   // self loop
    int k = beg;
    for (; k + 3 < end; k += 4) {
        int s0 = csr_src[k + 0], s1 = csr_src[k + 1];
        int s2 = csr_src[k + 2], s3 = csr_src[k + 3];
        float w0 = csr_w[k + 0], w1 = csr_w[k + 1];
        float w2 = csr_w[k + 2], w3 = csr_w[k + 3];
        float v0 = hin[(size_t)s0 * HID + j];
        float v1 = hin[(size_t)s1 * HID + j];
        float v2 = hin[(size_t)s2 * HID + j];
        float v3 = hin[(size_t)s3 * HID + j];
        acc += v0 * w0 + v1 * w1 + v2 * w2 + v3 * w3;
    }
    for (; k < end; ++k) {
        int s = csr_src[k];
        acc += hin[(size_t)s * HID + j] * csr_w[k];
    }
    acc += bias[j];
    if (relu) acc = fmaxf(acc, 0.f);
    out[(size_t)n * HID + j] = acc;
}

// ---------------- final linear: out = pooled @ Wl + bl ----------------
__global__ void k_final_init(const float* __restrict__ bl, float* __restrict__ out, int total) {
    int t = blockIdx.x * blockDim.x + threadIdx.x;
    if (t < total) out[t] = bl[t & (HID - 1)];
}

#define FR  8      // g-rows per block
#define FKC 800    // K-chunk (6400 / 8)
__global__ void k_final(const float* __restrict__ emb, const float* __restrict__ Wl,
                        float* __restrict__ out, int G) {
    int g0 = blockIdx.x * FR;
    int c  = blockIdx.y;
    int j  = threadIdx.x;
    int k0 = c * FKC;
    const float* pr = emb + (size_t)g0 * (SSUB * HID) + k0;
    float acc[FR] = {};
#pragma unroll 4
    for (int k = 0; k < FKC; ++k) {
        float w = Wl[(size_t)(k0 + k) * HID + j];
#pragma unroll
        for (int r = 0; r < FR; ++r)
            acc[r] += pr[(size_t)r * (SSUB * HID) + k] * w;
    }
#pragma unroll
    for (int r = 0; r < FR; ++r)
        atomicAdd(&out[(size_t)(g0 + r) * HID + j], acc[r]);
}

extern "C" void kernel_launch(void* const* d_in, const int* in_sizes, int n_in,
                              void* d_out, int out_size, void* d_ws, size_t ws_size,
                              hipStream_t stream) {
    const float* x  = (const float*)d_in[0];
    const float* W1 = (const float*)d_in[1];
    const float* b1 = (const float*)d_in[2];
    const float* W2 = (const float*)d_in[3];
    const float* b2 = (const float*)d_in[4];
    const float* Wl = (const float*)d_in[5];
    const float* bl = (const float*)d_in[6];
    const int* edge = (const int*)d_in[7];

    const int N = in_sizes[0] / F_IN;       // 50000
    const int E = in_sizes[7] / 2;          // 1600000
    const int G = N / SSUB;                 // 1000
    const int NH = N * HID;
    const int nblk = (N + 255) / 256;       // 196

    const int* src = edge;
    const int* dst = edge + E;

    // workspace layout
    char* ws = (char*)d_ws;
    float* dinv    = (float*)ws;                 ws += (size_t)N * 4;
    int*   cnt     = (int*)ws;                   ws += (size_t)N * 4;
    int*   row_ptr = (int*)ws;                   ws += (size_t)(N + 64) * 4;
    int*   cursor  = (int*)ws;                   ws += (size_t)N * 4;
    int*   blk_sum = (int*)ws;                   ws += (size_t)(nblk + 64) * 4;
    int*   blk_off = (int*)ws;                   ws += (size_t)(nblk + 64) * 4;
    int*   csr_src = (int*)ws;                   ws += (size_t)E * 4;
    float* csr_w   = (float*)ws;                 ws += (size_t)E * 4;
    float* h0      = (float*)ws;                 ws += (size_t)NH * 4;
    float* h       = (float*)ws;                 ws += (size_t)NH * 4;
    float* h1      = h0;                         // reuse after layer-1 agg

    float* out_final = (float*)d_out;                 // G*H
    float* emb       = out_final + (size_t)G * HID;   // N*H

    // ---- CSR build (also computes dinv) ----
    k_zero_int<<<(N + 255) / 256, 256, 0, stream>>>(cnt, N);
    k_hist<<<(E + 255) / 256, 256, 0, stream>>>(dst, cnt, E);
    k_scan_local<<<nblk, 256, 0, stream>>>(cnt, row_ptr, dinv, blk_sum, N);
    k_scan_blk<<<1, 256, 0, stream>>>(blk_sum, blk_off, nblk);
    k_scan_add<<<nblk, 256, 0, stream>>>(row_ptr, cursor, blk_off, N, nblk);
    k_fill_csr<<<(E + 255) / 256, 256, 0, stream>>>(src, dst, dinv, cursor, csr_src, csr_w, E);

    // ---- layer 1 ----
    k_gemm1<<<N / G1R, 128, 0, stream>>>(x, W1, h0, N);
    k_agg<<<N, 128, 0, stream>>>(h0, row_ptr, csr_src, csr_w, dinv, b1, h, 1);

    // ---- layer 2 ----
    k_gemm2<<<N / G1R, 128, 0, stream>>>(h, W2, h1, N);
    k_agg<<<N, 128, 0, stream>>>(h1, row_ptr, csr_src, csr_w, dinv, b2, emb, 0);

    // ---- final linear ----
    k_final_init<<<(G * HID + 255) / 256, 256, 0, stream>>>(bl, out_final, G * HID);
    {
        dim3 grid(G / FR, (SSUB * HID) / FKC);
        k_final<<<grid, 128, 0, stream>>>(emb, Wl, out_final, G);
    }
}

// Round 5
// 710.992 us; speedup vs baseline: 8.8096x; 1.2254x over previous
//
#include <hip/hip_runtime.h>
#include <hip/hip_bf16.h>

#define F_IN 256
#define HID  128
#define SSUB 50

typedef __attribute__((ext_vector_type(4))) float f32x4;
typedef __attribute__((ext_vector_type(8))) short bf16x8;

__device__ __forceinline__ void split_bf16(float v, short& hi, short& lo) {
    __hip_bfloat16 h = __float2bfloat16(v);
    float hf = __bfloat162float(h);
    __hip_bfloat16 l = __float2bfloat16(v - hf);   // exact residual, then RNE to bf16
    hi = __builtin_bit_cast(short, h);
    lo = __builtin_bit_cast(short, l);
}

// ---------------- CSR build ----------------

__global__ void k_zero_int(int* __restrict__ p, int n) {
    int i = blockIdx.x * blockDim.x + threadIdx.x;
    if (i < n) p[i] = 0;
}

__global__ void k_hist(const int* __restrict__ dst, int* __restrict__ cnt, int E) {
    int e = blockIdx.x * blockDim.x + threadIdx.x;
    if (e < E) atomicAdd(&cnt[dst[e]], 1);
}

// ---- hierarchical exclusive scan over cnt[0..N) ----
__global__ void k_scan_local(const int* __restrict__ cnt, int* __restrict__ row_ptr,
                             float* __restrict__ dinv, int* __restrict__ blk_sum, int N) {
    __shared__ int buf[256];
    int tid = threadIdx.x;
    int i = blockIdx.x * 256 + tid;
    int v = (i < N) ? cnt[i] : 0;
    buf[tid] = v;
    __syncthreads();
    for (int off = 1; off < 256; off <<= 1) {
        int t = (tid >= off) ? buf[tid - off] : 0;
        __syncthreads();
        buf[tid] += t;
        __syncthreads();
    }
    if (i < N) {
        row_ptr[i] = buf[tid] - v;
        dinv[i] = rsqrtf((float)(v + 1));   // +1 self loop
    }
    if (tid == 255) blk_sum[blockIdx.x] = buf[255];
}

__global__ void k_scan_blk(const int* __restrict__ blk_sum, int* __restrict__ blk_off, int nblk) {
    __shared__ int buf[256];
    int tid = threadIdx.x;
    int v = (tid < nblk) ? blk_sum[tid] : 0;
    buf[tid] = v;
    __syncthreads();
    for (int off = 1; off < 256; off <<= 1) {
        int t = (tid >= off) ? buf[tid - off] : 0;
        __syncthreads();
        buf[tid] += t;
        __syncthreads();
    }
    if (tid < nblk) blk_off[tid] = buf[tid] - v;
    if (tid == 255) blk_off[nblk] = buf[255];
}

__global__ void k_scan_add(int* __restrict__ row_ptr, int* __restrict__ cursor,
                           const int* __restrict__ blk_off, int N, int nblk) {
    int i = blockIdx.x * 256 + threadIdx.x;
    if (i < N) {
        int val = row_ptr[i] + blk_off[blockIdx.x];
        row_ptr[i] = val;
        cursor[i] = val;
    }
    if (i == 0) row_ptr[N] = blk_off[nblk];
}

__global__ void k_fill_csr(const int* __restrict__ src, const int* __restrict__ dst,
                           const float* __restrict__ dinv, int* __restrict__ cursor,
                           int* __restrict__ csr_src, float* __restrict__ csr_w, int E) {
    int e = blockIdx.x * blockDim.x + threadIdx.x;
    if (e >= E) return;
    int s = src[e];
    int d = dst[e];
    int pos = atomicAdd(&cursor[d], 1);
    csr_src[pos] = s;
    csr_w[pos] = dinv[s] * dinv[d];
}

// ---------------- W split: fp32 (K x 128) -> fragment-linear bf16 hi/lo ----------------
// layout (elements): [part][kc][nt][lane][j], lane=(quad<<4)|(n&15), j=k&7, part stride K*HID
template<int K>
__global__ void k_wsplit(const float* __restrict__ W, short* __restrict__ Bf) {
    int t = blockIdx.x * 256 + threadIdx.x;
    if (t >= K * HID) return;
    int k = t >> 7, n = t & 127;
    short hi, lo;
    split_bf16(W[t], hi, lo);
    int kc = k >> 5, ko = k & 31;
    int quad = ko >> 3, j = ko & 7;
    int nt = n >> 4, nc = n & 15;
    int lane = (quad << 4) | nc;
    size_t idx = (((size_t)(kc * 8 + nt)) * 64 + lane) * 8 + j;
    Bf[idx] = hi;
    Bf[(size_t)K * HID + idx] = lo;
}

// ---------------- MFMA GEMM: C(MxHID) = A(MxK, fp32) @ W via bf16 2-term split ----------------
// block = 128 threads (2 waves), M-tile = 32 rows (16 per wave), N = 128 (8 n-tiles)
template<int K>
__global__ __launch_bounds__(128) void k_gemm_mfma(const float* __restrict__ A,
                                                   const short* __restrict__ Bf,
                                                   float* __restrict__ C, int M) {
    constexpr int LDA = K + 4;       // pad to break bank alignment
    constexpr int KC = K / 32;
    __shared__ float As[32 * LDA];
    int tid = threadIdx.x;
    int base = blockIdx.x * 32;

    // stage 32 x K fp32 tile (coalesced float4 loads), zero-fill beyond M
    constexpr int ITERS = (32 * (K / 4)) / 128;
#pragma unroll
    for (int i = 0; i < ITERS; ++i) {
        int f4 = tid + i * 128;
        int row = f4 / (K / 4);
        int c4 = f4 % (K / 4);
        f32x4 v = {0.f, 0.f, 0.f, 0.f};
        int m = base + row;
        if (m < M) v = *(const f32x4*)(A + (size_t)m * K + c4 * 4);
        *(f32x4*)(&As[row * LDA + c4 * 4]) = v;
    }
    __syncthreads();

    int lane = tid & 63;
    int w = tid >> 6;                 // wave id: rows [w*16, w*16+16)
    int quad = lane >> 4;
    int mrow = w * 16 + (lane & 15);  // local row this lane's A-fragment covers
    f32x4 acc[8] = {};
    const bf16x8* BfH = (const bf16x8*)Bf;
    const bf16x8* BfL = (const bf16x8*)(Bf + (size_t)K * HID);

    for (int kc = 0; kc < KC; ++kc) {
        // A fragment: 8 contiguous fp32 -> split into hi/lo bf16x8
        const float* ap = &As[mrow * LDA + kc * 32 + quad * 8];
        f32x4 a0 = *(const f32x4*)ap;
        f32x4 a1 = *(const f32x4*)(ap + 4);
        bf16x8 ahi, alo;
#pragma unroll
        for (int j2 = 0; j2 < 4; ++j2) {
            short hi, lo;
            split_bf16(a0[j2], hi, lo);
            ahi[j2] = hi; alo[j2] = lo;
            split_bf16(a1[j2], hi, lo);
            ahi[4 + j2] = hi; alo[4 + j2] = lo;
        }
        // B fragments: coalesced b128 loads from fragment-linear layout (L2-hot)
        bf16x8 bh[8], bl[8];
        size_t boff = ((size_t)kc * 8) * 64 + lane;
#pragma unroll
        for (int nt = 0; nt < 8; ++nt) {
            bh[nt] = BfH[boff + (size_t)nt * 64];
            bl[nt] = BfL[boff + (size_t)nt * 64];
        }
#pragma unroll
        for (int nt = 0; nt < 8; ++nt)
            acc[nt] = __builtin_amdgcn_mfma_f32_16x16x32_bf16(ahi, bh[nt], acc[nt], 0, 0, 0);
#pragma unroll
        for (int nt = 0; nt < 8; ++nt)
            acc[nt] = __builtin_amdgcn_mfma_f32_16x16x32_bf16(alo, bh[nt], acc[nt], 0, 0, 0);
#pragma unroll
        for (int nt = 0; nt < 8; ++nt)
            acc[nt] = __builtin_amdgcn_mfma_f32_16x16x32_bf16(ahi, bl[nt], acc[nt], 0, 0, 0);
    }

    // store: C/D layout col=lane&15, row=quad*4+reg
    int mbase = base + w * 16 + quad * 4;
    int ncol = lane & 15;
#pragma unroll
    for (int nt = 0; nt < 8; ++nt) {
#pragma unroll
        for (int r = 0; r < 4; ++r) {
            int m = mbase + r;
            if (m < M) C[(size_t)m * HID + nt * 16 + ncol] = acc[nt][r];
        }
    }
}

// ---------------- CSR aggregation, fused self-loop + bias (+relu) ----------------
__global__ void k_agg(const float* __restrict__ hin, const int* __restrict__ row_ptr,
                      const int* __restrict__ csr_src, const float* __restrict__ csr_w,
                      const float* __restrict__ dinv, const float* __restrict__ bias,
                      float* __restrict__ out, int relu) {
    int n = blockIdx.x;
    int j = threadIdx.x;
    int beg = row_ptr[n];
    int end = row_ptr[n + 1];
    float d = dinv[n];
    float acc = hin[(size_t)n * HID + j] * d * d;   // self loop
    int k = beg;
    for (; k + 3 < end; k += 4) {
        int s0 = csr_src[k + 0], s1 = csr_src[k + 1];
        int s2 = csr_src[k + 2], s3 = csr_src[k + 3];
        float w0 = csr_w[k + 0], w1 = csr_w[k + 1];
        float w2 = csr_w[k + 2], w3 = csr_w[k + 3];
        float v0 = hin[(size_t)s0 * HID + j];
        float v1 = hin[(size_t)s1 * HID + j];
        float v2 = hin[(size_t)s2 * HID + j];
        float v3 = hin[(size_t)s3 * HID + j];
        acc += v0 * w0 + v1 * w1 + v2 * w2 + v3 * w3;
    }
    for (; k < end; ++k) {
        int s = csr_src[k];
        acc += hin[(size_t)s * HID + j] * csr_w[k];
    }
    acc += bias[j];
    if (relu) acc = fmaxf(acc, 0.f);
    out[(size_t)n * HID + j] = acc;
}

// ---------------- final linear: out = pooled @ Wl + bl ----------------
__global__ void k_final_init(const float* __restrict__ bl, float* __restrict__ out, int total) {
    int t = blockIdx.x * blockDim.x + threadIdx.x;
    if (t < total) out[t] = bl[t & (HID - 1)];
}

#define FR  8      // g-rows per block
#define FKC 800    // K-chunk (6400 / 8)
__global__ void k_final(const float* __restrict__ emb, const float* __restrict__ Wl,
                        float* __restrict__ out, int G) {
    int g0 = blockIdx.x * FR;
    int c  = blockIdx.y;
    int j  = threadIdx.x;
    int k0 = c * FKC;
    const float* pr = emb + (size_t)g0 * (SSUB * HID) + k0;
    float acc[FR] = {};
#pragma unroll 4
    for (int k = 0; k < FKC; ++k) {
        float w = Wl[(size_t)(k0 + k) * HID + j];
#pragma unroll
        for (int r = 0; r < FR; ++r)
            acc[r] += pr[(size_t)r * (SSUB * HID) + k] * w;
    }
#pragma unroll
    for (int r = 0; r < FR; ++r)
        atomicAdd(&out[(size_t)(g0 + r) * HID + j], acc[r]);
}

extern "C" void kernel_launch(void* const* d_in, const int* in_sizes, int n_in,
                              void* d_out, int out_size, void* d_ws, size_t ws_size,
                              hipStream_t stream) {
    const float* x  = (const float*)d_in[0];
    const float* W1 = (const float*)d_in[1];
    const float* b1 = (const float*)d_in[2];
    const float* W2 = (const float*)d_in[3];
    const float* b2 = (const float*)d_in[4];
    const float* Wl = (const float*)d_in[5];
    const float* bl = (const float*)d_in[6];
    const int* edge = (const int*)d_in[7];

    const int N = in_sizes[0] / F_IN;       // 50000
    const int E = in_sizes[7] / 2;          // 1600000
    const int G = N / SSUB;                 // 1000
    const int NH = N * HID;
    const int nblk = (N + 255) / 256;       // 196

    const int* src = edge;
    const int* dst = edge + E;

    // workspace layout
    char* ws = (char*)d_ws;
    float* dinv    = (float*)ws;                 ws += (size_t)N * 4;
    int*   cnt     = (int*)ws;                   ws += (size_t)N * 4;
    int*   row_ptr = (int*)ws;                   ws += (size_t)(N + 64) * 4;
    int*   cursor  = (int*)ws;                   ws += (size_t)N * 4;
    int*   blk_sum = (int*)ws;                   ws += (size_t)(nblk + 64) * 4;
    int*   blk_off = (int*)ws;                   ws += (size_t)(nblk + 64) * 4;
    int*   csr_src = (int*)ws;                   ws += (size_t)E * 4;
    float* csr_w   = (float*)ws;                 ws += (size_t)E * 4;
    float* h0      = (float*)ws;                 ws += (size_t)NH * 4;
    float* h       = (float*)ws;                 ws += (size_t)NH * 4;
    short* Bf1     = (short*)ws;                 ws += (size_t)2 * F_IN * HID * 2;  // hi+lo bf16
    short* Bf2     = (short*)ws;                 ws += (size_t)2 * HID * HID * 2;
    float* h1      = h0;                         // reuse after layer-1 agg

    float* out_final = (float*)d_out;                 // G*H
    float* emb       = out_final + (size_t)G * HID;   // N*H

    // ---- CSR build (also computes dinv) ----
    k_zero_int<<<(N + 255) / 256, 256, 0, stream>>>(cnt, N);
    k_hist<<<(E + 255) / 256, 256, 0, stream>>>(dst, cnt, E);
    k_scan_local<<<nblk, 256, 0, stream>>>(cnt, row_ptr, dinv, blk_sum, N);
    k_scan_blk<<<1, 256, 0, stream>>>(blk_sum, blk_off, nblk);
    k_scan_add<<<nblk, 256, 0, stream>>>(row_ptr, cursor, blk_off, N, nblk);
    k_fill_csr<<<(E + 255) / 256, 256, 0, stream>>>(src, dst, dinv, cursor, csr_src, csr_w, E);

    // ---- weight splits (cheap, every call) ----
    k_wsplit<F_IN><<<(F_IN * HID + 255) / 256, 256, 0, stream>>>(W1, Bf1);
    k_wsplit<HID ><<<(HID  * HID + 255) / 256, 256, 0, stream>>>(W2, Bf2);

    // ---- layer 1 ----
    k_gemm_mfma<F_IN><<<(N + 31) / 32, 128, 0, stream>>>(x, Bf1, h0, N);
    k_agg<<<N, 128, 0, stream>>>(h0, row_ptr, csr_src, csr_w, dinv, b1, h, 1);

    // ---- layer 2 ----
    k_gemm_mfma<HID><<<(N + 31) / 32, 128, 0, stream>>>(h, Bf2, h1, N);
    k_agg<<<N, 128, 0, stream>>>(h1, row_ptr, csr_src, csr_w, dinv, b2, emb, 0);

    // ---- final linear ----
    k_final_init<<<(G * HID + 255) / 256, 256, 0, stream>>>(bl, out_final, G * HID);
    {
        dim3 grid(G / FR, (SSUB * HID) / FKC);
        k_final<<<grid, 128, 0, stream>>>(emb, Wl, out_final, G);
    }
}

// Round 6
// 671.502 us; speedup vs baseline: 9.3277x; 1.0588x over previous
//
#include <hip/hip_runtime.h>
#include <hip/hip_bf16.h>

#define F_IN 256
#define HID  128
#define SSUB 50

typedef __attribute__((ext_vector_type(4))) float f32x4;
typedef __attribute__((ext_vector_type(8))) short bf16x8;

__device__ __forceinline__ void split_bf16(float v, short& hi, short& lo) {
    __hip_bfloat16 h = __float2bfloat16(v);
    float hf = __bfloat162float(h);
    __hip_bfloat16 l = __float2bfloat16(v - hf);   // exact residual, then RNE to bf16
    hi = __builtin_bit_cast(short, h);
    lo = __builtin_bit_cast(short, l);
}

// ---------------- CSR build ----------------

__global__ void k_zero_int(int* __restrict__ p, int n) {
    int i = blockIdx.x * blockDim.x + threadIdx.x;
    if (i < n) p[i] = 0;
}

__global__ void k_hist(const int* __restrict__ dst, int* __restrict__ cnt, int E) {
    int e = blockIdx.x * blockDim.x + threadIdx.x;
    if (e < E) atomicAdd(&cnt[dst[e]], 1);
}

// ---- hierarchical exclusive scan over cnt[0..N) ----
__global__ void k_scan_local(const int* __restrict__ cnt, int* __restrict__ row_ptr,
                             float* __restrict__ dinv, int* __restrict__ blk_sum, int N) {
    __shared__ int buf[256];
    int tid = threadIdx.x;
    int i = blockIdx.x * 256 + tid;
    int v = (i < N) ? cnt[i] : 0;
    buf[tid] = v;
    __syncthreads();
    for (int off = 1; off < 256; off <<= 1) {
        int t = (tid >= off) ? buf[tid - off] : 0;
        __syncthreads();
        buf[tid] += t;
        __syncthreads();
    }
    if (i < N) {
        row_ptr[i] = buf[tid] - v;
        dinv[i] = rsqrtf((float)(v + 1));   // +1 self loop
    }
    if (tid == 255) blk_sum[blockIdx.x] = buf[255];
}

__global__ void k_scan_blk(const int* __restrict__ blk_sum, int* __restrict__ blk_off, int nblk) {
    __shared__ int buf[256];
    int tid = threadIdx.x;
    int v = (tid < nblk) ? blk_sum[tid] : 0;
    buf[tid] = v;
    __syncthreads();
    for (int off = 1; off < 256; off <<= 1) {
        int t = (tid >= off) ? buf[tid - off] : 0;
        __syncthreads();
        buf[tid] += t;
        __syncthreads();
    }
    if (tid < nblk) blk_off[tid] = buf[tid] - v;
    if (tid == 255) blk_off[nblk] = buf[255];
}

__global__ void k_scan_add(int* __restrict__ row_ptr, int* __restrict__ cursor,
                           const int* __restrict__ blk_off, int N, int nblk) {
    int i = blockIdx.x * 256 + threadIdx.x;
    if (i < N) {
        int val = row_ptr[i] + blk_off[blockIdx.x];
        row_ptr[i] = val;
        cursor[i] = val;
    }
    if (i == 0) row_ptr[N] = blk_off[nblk];
}

// XCD-sliced CSR fill: block (chunk, slice) scans its 256-edge chunk, scatters only
// edges whose dst lies in its slice. blockIdx%8 -> XCD round-robin (perf heuristic
// only): each CSR line then gets written by ~one XCD -> no cross-XCD line ping-pong.
__global__ void k_fill_csr(const int* __restrict__ src, const int* __restrict__ dst,
                           int* __restrict__ cursor, int* __restrict__ csr_src,
                           int E, int slice_size) {
    int slice = blockIdx.x & 7;
    int e = (blockIdx.x >> 3) * 256 + threadIdx.x;
    if (e >= E) return;
    int d = dst[e];
    if (d / slice_size != slice) return;
    int pos = atomicAdd(&cursor[d], 1);
    csr_src[pos] = src[e];
}

// ---------------- W split: fp32 (K x 128) -> fragment-linear bf16 hi/lo ----------------
template<int K>
__global__ void k_wsplit(const float* __restrict__ W, short* __restrict__ Bf) {
    int t = blockIdx.x * 256 + threadIdx.x;
    if (t >= K * HID) return;
    int k = t >> 7, n = t & 127;
    short hi, lo;
    split_bf16(W[t], hi, lo);
    int kc = k >> 5, ko = k & 31;
    int quad = ko >> 3, j = ko & 7;
    int nt = n >> 4, nc = n & 15;
    int lane = (quad << 4) | nc;
    size_t idx = (((size_t)(kc * 8 + nt)) * 64 + lane) * 8 + j;
    Bf[idx] = hi;
    Bf[(size_t)K * HID + idx] = lo;
}

// ---------------- MFMA GEMM: C(MxHID) = (A(MxK, fp32) @ W) * dinv[row] ----------------
// block = 128 threads (2 waves), M-tile = 32 rows (16 per wave), N = 128 (8 n-tiles)
template<int K>
__global__ __launch_bounds__(128) void k_gemm_mfma(const float* __restrict__ A,
                                                   const short* __restrict__ Bf,
                                                   const float* __restrict__ dinv,
                                                   float* __restrict__ C, int M) {
    constexpr int LDA = K + 4;
    constexpr int KC = K / 32;
    __shared__ float As[32 * LDA];
    int tid = threadIdx.x;
    int base = blockIdx.x * 32;

    constexpr int ITERS = (32 * (K / 4)) / 128;
#pragma unroll
    for (int i = 0; i < ITERS; ++i) {
        int f4 = tid + i * 128;
        int row = f4 / (K / 4);
        int c4 = f4 % (K / 4);
        f32x4 v = {0.f, 0.f, 0.f, 0.f};
        int m = base + row;
        if (m < M) v = *(const f32x4*)(A + (size_t)m * K + c4 * 4);
        *(f32x4*)(&As[row * LDA + c4 * 4]) = v;
    }
    __syncthreads();

    int lane = tid & 63;
    int w = tid >> 6;
    int quad = lane >> 4;
    int mrow = w * 16 + (lane & 15);
    f32x4 acc[8] = {};
    const bf16x8* BfH = (const bf16x8*)Bf;
    const bf16x8* BfL = (const bf16x8*)(Bf + (size_t)K * HID);

    for (int kc = 0; kc < KC; ++kc) {
        const float* ap = &As[mrow * LDA + kc * 32 + quad * 8];
        f32x4 a0 = *(const f32x4*)ap;
        f32x4 a1 = *(const f32x4*)(ap + 4);
        bf16x8 ahi, alo;
#pragma unroll
        for (int j2 = 0; j2 < 4; ++j2) {
            short hi, lo;
            split_bf16(a0[j2], hi, lo);
            ahi[j2] = hi; alo[j2] = lo;
            split_bf16(a1[j2], hi, lo);
            ahi[4 + j2] = hi; alo[4 + j2] = lo;
        }
        bf16x8 bh[8], bl[8];
        size_t boff = ((size_t)kc * 8) * 64 + lane;
#pragma unroll
        for (int nt = 0; nt < 8; ++nt) {
            bh[nt] = BfH[boff + (size_t)nt * 64];
            bl[nt] = BfL[boff + (size_t)nt * 64];
        }
#pragma unroll
        for (int nt = 0; nt < 8; ++nt)
            acc[nt] = __builtin_amdgcn_mfma_f32_16x16x32_bf16(ahi, bh[nt], acc[nt], 0, 0, 0);
#pragma unroll
        for (int nt = 0; nt < 8; ++nt)
            acc[nt] = __builtin_amdgcn_mfma_f32_16x16x32_bf16(alo, bh[nt], acc[nt], 0, 0, 0);
#pragma unroll
        for (int nt = 0; nt < 8; ++nt)
            acc[nt] = __builtin_amdgcn_mfma_f32_16x16x32_bf16(ahi, bl[nt], acc[nt], 0, 0, 0);
    }

    // epilogue: scale row by dinv[m]; C/D layout col=lane&15, row=quad*4+reg
    int mbase = base + w * 16 + quad * 4;
    int ncol = lane & 15;
    float dsc[4];
#pragma unroll
    for (int r = 0; r < 4; ++r)
        dsc[r] = (mbase + r < M) ? dinv[mbase + r] : 0.f;
#pragma unroll
    for (int nt = 0; nt < 8; ++nt) {
#pragma unroll
        for (int r = 0; r < 4; ++r) {
            int m = mbase + r;
            if (m < M) C[(size_t)m * HID + nt * 16 + ncol] = acc[nt][r] * dsc[r];
        }
    }
}

// ---------------- CSR aggregation (unweighted; inputs pre-scaled by dinv[src]) ----------------
// out[n] = dinv[n] * (hs[n] + sum_in hs[src]) + bias  (+relu)
__global__ void k_agg(const float* __restrict__ hs, const int* __restrict__ row_ptr,
                      const int* __restrict__ csr_src, const float* __restrict__ dinv,
                      const float* __restrict__ bias, float* __restrict__ out, int relu) {
    int n = blockIdx.x;
    int j = threadIdx.x;
    int beg = row_ptr[n];
    int end = row_ptr[n + 1];
    float acc = hs[(size_t)n * HID + j];   // self loop (pre-scaled)
    int k = beg;
    for (; k + 3 < end; k += 4) {
        int s0 = csr_src[k + 0], s1 = csr_src[k + 1];
        int s2 = csr_src[k + 2], s3 = csr_src[k + 3];
        float v0 = hs[(size_t)s0 * HID + j];
        float v1 = hs[(size_t)s1 * HID + j];
        float v2 = hs[(size_t)s2 * HID + j];
        float v3 = hs[(size_t)s3 * HID + j];
        acc += (v0 + v1) + (v2 + v3);
    }
    for (; k < end; ++k)
        acc += hs[(size_t)csr_src[k] * HID + j];
    acc = acc * dinv[n] + bias[j];
    if (relu) acc = fmaxf(acc, 0.f);
    out[(size_t)n * HID + j] = acc;
}

// ---------------- final linear: out = pooled @ Wl + bl ----------------
__global__ void k_final_init(const float* __restrict__ bl, float* __restrict__ out, int total) {
    int t = blockIdx.x * blockDim.x + threadIdx.x;
    if (t < total) out[t] = bl[t & (HID - 1)];
}

#define FR  8      // g-rows per block
#define FKC 800    // K-chunk (6400 / 8)
__global__ void k_final(const float* __restrict__ emb, const float* __restrict__ Wl,
                        float* __restrict__ out, int G) {
    int g0 = blockIdx.x * FR;
    int c  = blockIdx.y;
    int j  = threadIdx.x;
    int k0 = c * FKC;
    const float* pr = emb + (size_t)g0 * (SSUB * HID) + k0;
    float acc[FR] = {};
#pragma unroll 4
    for (int k = 0; k < FKC; ++k) {
        float w = Wl[(size_t)(k0 + k) * HID + j];
#pragma unroll
        for (int r = 0; r < FR; ++r)
            acc[r] += pr[(size_t)r * (SSUB * HID) + k] * w;
    }
#pragma unroll
    for (int r = 0; r < FR; ++r)
        atomicAdd(&out[(size_t)(g0 + r) * HID + j], acc[r]);
}

extern "C" void kernel_launch(void* const* d_in, const int* in_sizes, int n_in,
                              void* d_out, int out_size, void* d_ws, size_t ws_size,
                              hipStream_t stream) {
    const float* x  = (const float*)d_in[0];
    const float* W1 = (const float*)d_in[1];
    const float* b1 = (const float*)d_in[2];
    const float* W2 = (const float*)d_in[3];
    const float* b2 = (const float*)d_in[4];
    const float* Wl = (const float*)d_in[5];
    const float* bl = (const float*)d_in[6];
    const int* edge = (const int*)d_in[7];

    const int N = in_sizes[0] / F_IN;       // 50000
    const int E = in_sizes[7] / 2;          // 1600000
    const int G = N / SSUB;                 // 1000
    const int NH = N * HID;
    const int nblk = (N + 255) / 256;       // 196
    const int slice_size = (N + 7) / 8;     // 6250

    const int* src = edge;
    const int* dst = edge + E;

    // workspace layout
    char* ws = (char*)d_ws;
    float* dinv    = (float*)ws;                 ws += (size_t)N * 4;
    int*   cnt     = (int*)ws;                   ws += (size_t)N * 4;
    int*   row_ptr = (int*)ws;                   ws += (size_t)(N + 64) * 4;
    int*   cursor  = (int*)ws;                   ws += (size_t)N * 4;
    int*   blk_sum = (int*)ws;                   ws += (size_t)(nblk + 64) * 4;
    int*   blk_off = (int*)ws;                   ws += (size_t)(nblk + 64) * 4;
    int*   csr_src = (int*)ws;                   ws += (size_t)E * 4;
    float* h0      = (float*)ws;                 ws += (size_t)NH * 4;
    float* h       = (float*)ws;                 ws += (size_t)NH * 4;
    short* Bf1     = (short*)ws;                 ws += (size_t)2 * F_IN * HID * 2;  // hi+lo bf16
    short* Bf2     = (short*)ws;                 ws += (size_t)2 * HID * HID * 2;
    float* h1      = h0;                         // reuse after layer-1 agg

    float* out_final = (float*)d_out;                 // G*H
    float* emb       = out_final + (size_t)G * HID;   // N*H

    // ---- CSR build (also computes dinv) ----
    k_zero_int<<<(N + 255) / 256, 256, 0, stream>>>(cnt, N);
    k_hist<<<(E + 255) / 256, 256, 0, stream>>>(dst, cnt, E);
    k_scan_local<<<nblk, 256, 0, stream>>>(cnt, row_ptr, dinv, blk_sum, N);
    k_scan_blk<<<1, 256, 0, stream>>>(blk_sum, blk_off, nblk);
    k_scan_add<<<nblk, 256, 0, stream>>>(row_ptr, cursor, blk_off, N, nblk);
    {
        int chunks = (E + 255) / 256;
        k_fill_csr<<<chunks * 8, 256, 0, stream>>>(src, dst, cursor, csr_src, E, slice_size);
    }

    // ---- weight splits ----
    k_wsplit<F_IN><<<(F_IN * HID + 255) / 256, 256, 0, stream>>>(W1, Bf1);
    k_wsplit<HID ><<<(HID  * HID + 255) / 256, 256, 0, stream>>>(W2, Bf2);

    // ---- layer 1 ----
    k_gemm_mfma<F_IN><<<(N + 31) / 32, 128, 0, stream>>>(x, Bf1, dinv, h0, N);   // h0 = (x@W1)*dinv
    k_agg<<<N, 128, 0, stream>>>(h0, row_ptr, csr_src, dinv, b1, h, 1);

    // ---- layer 2 ----
    k_gemm_mfma<HID><<<(N + 31) / 32, 128, 0, stream>>>(h, Bf2, dinv, h1, N);    // h1 = (h@W2)*dinv
    k_agg<<<N, 128, 0, stream>>>(h1, row_ptr, csr_src, dinv, b2, emb, 0);

    // ---- final linear ----
    k_final_init<<<(G * HID + 255) / 256, 256, 0, stream>>>(bl, out_final, G * HID);
    {
        dim3 grid(G / FR, (SSUB * HID) / FKC);
        k_final<<<grid, 128, 0, stream>>>(emb, Wl, out_final, G);
    }
}

// Round 7
// 577.697 us; speedup vs baseline: 10.8423x; 1.1624x over previous
//
#include <hip/hip_runtime.h>
#include <hip/hip_bf16.h>

#define F_IN 256
#define HID  128
#define SSUB 50

typedef __attribute__((ext_vector_type(4))) float f32x4;
typedef __attribute__((ext_vector_type(8))) short bf16x8;

__device__ __forceinline__ void split_bf16(float v, short& hi, short& lo) {
    __hip_bfloat16 h = __float2bfloat16(v);
    float hf = __bfloat162float(h);
    __hip_bfloat16 l = __float2bfloat16(v - hf);   // exact residual, then RNE to bf16
    hi = __builtin_bit_cast(short, h);
    lo = __builtin_bit_cast(short, l);
}

__device__ __forceinline__ float bf2f(unsigned short u) {
    return __builtin_bit_cast(float, (unsigned)u << 16);
}

// ---------------- CSR build ----------------

__global__ void k_zero_int(int* __restrict__ p, int n) {
    int i = blockIdx.x * blockDim.x + threadIdx.x;
    if (i < n) p[i] = 0;
}

__global__ void k_hist(const int* __restrict__ dst, int* __restrict__ cnt, int E) {
    int e = blockIdx.x * blockDim.x + threadIdx.x;
    if (e < E) atomicAdd(&cnt[dst[e]], 1);
}

// ---- hierarchical exclusive scan over cnt[0..N) ----
__global__ void k_scan_local(const int* __restrict__ cnt, int* __restrict__ row_ptr,
                             float* __restrict__ dinv, int* __restrict__ blk_sum, int N) {
    __shared__ int buf[256];
    int tid = threadIdx.x;
    int i = blockIdx.x * 256 + tid;
    int v = (i < N) ? cnt[i] : 0;
    buf[tid] = v;
    __syncthreads();
    for (int off = 1; off < 256; off <<= 1) {
        int t = (tid >= off) ? buf[tid - off] : 0;
        __syncthreads();
        buf[tid] += t;
        __syncthreads();
    }
    if (i < N) {
        row_ptr[i] = buf[tid] - v;
        dinv[i] = rsqrtf((float)(v + 1));   // +1 self loop
    }
    if (tid == 255) blk_sum[blockIdx.x] = buf[255];
}

__global__ void k_scan_blk(const int* __restrict__ blk_sum, int* __restrict__ blk_off, int nblk) {
    __shared__ int buf[256];
    int tid = threadIdx.x;
    int v = (tid < nblk) ? blk_sum[tid] : 0;
    buf[tid] = v;
    __syncthreads();
    for (int off = 1; off < 256; off <<= 1) {
        int t = (tid >= off) ? buf[tid - off] : 0;
        __syncthreads();
        buf[tid] += t;
        __syncthreads();
    }
    if (tid < nblk) blk_off[tid] = buf[tid] - v;
    if (tid == 255) blk_off[nblk] = buf[255];
}

__global__ void k_scan_add(int* __restrict__ row_ptr, int* __restrict__ cursor,
                           const int* __restrict__ blk_off, int N, int nblk) {
    int i = blockIdx.x * 256 + threadIdx.x;
    if (i < N) {
        int val = row_ptr[i] + blk_off[blockIdx.x];
        row_ptr[i] = val;
        cursor[i] = val;
    }
    if (i == 0) row_ptr[N] = blk_off[nblk];
}

// XCD-sliced CSR fill (blockIdx%8 -> XCD round-robin; perf heuristic only)
__global__ void k_fill_csr(const int* __restrict__ src, const int* __restrict__ dst,
                           int* __restrict__ cursor, int* __restrict__ csr_src,
                           int E, int slice_size) {
    int slice = blockIdx.x & 7;
    int e = (blockIdx.x >> 3) * 256 + threadIdx.x;
    if (e >= E) return;
    int d = dst[e];
    if (d / slice_size != slice) return;
    int pos = atomicAdd(&cursor[d], 1);
    csr_src[pos] = src[e];
}

// ---------------- W split: fp32 (K x 128) -> fragment-linear bf16 hi/lo ----------------
template<int K>
__global__ void k_wsplit(const float* __restrict__ W, short* __restrict__ Bf) {
    int t = blockIdx.x * 256 + threadIdx.x;
    if (t >= K * HID) return;
    int k = t >> 7, n = t & 127;
    short hi, lo;
    split_bf16(W[t], hi, lo);
    int kc = k >> 5, ko = k & 31;
    int quad = ko >> 3, j = ko & 7;
    int nt = n >> 4, nc = n & 15;
    int lane = (quad << 4) | nc;
    size_t idx = (((size_t)(kc * 8 + nt)) * 64 + lane) * 8 + j;
    Bf[idx] = hi;
    Bf[(size_t)K * HID + idx] = lo;
}

// ---------------- MFMA GEMM: Cb(MxHID, bf16) = (A(MxK, fp32) @ W) * dinv[row] ----------------
template<int K>
__global__ __launch_bounds__(128) void k_gemm_mfma(const float* __restrict__ A,
                                                   const short* __restrict__ Bf,
                                                   const float* __restrict__ dinv,
                                                   unsigned short* __restrict__ Cb, int M) {
    constexpr int LDA = K + 4;
    constexpr int KC = K / 32;
    __shared__ float As[32 * LDA];
    int tid = threadIdx.x;
    int base = blockIdx.x * 32;

    constexpr int ITERS = (32 * (K / 4)) / 128;
#pragma unroll
    for (int i = 0; i < ITERS; ++i) {
        int f4 = tid + i * 128;
        int row = f4 / (K / 4);
        int c4 = f4 % (K / 4);
        f32x4 v = {0.f, 0.f, 0.f, 0.f};
        int m = base + row;
        if (m < M) v = *(const f32x4*)(A + (size_t)m * K + c4 * 4);
        *(f32x4*)(&As[row * LDA + c4 * 4]) = v;
    }
    __syncthreads();

    int lane = tid & 63;
    int w = tid >> 6;
    int quad = lane >> 4;
    int mrow = w * 16 + (lane & 15);
    f32x4 acc[8] = {};
    const bf16x8* BfH = (const bf16x8*)Bf;
    const bf16x8* BfL = (const bf16x8*)(Bf + (size_t)K * HID);

    for (int kc = 0; kc < KC; ++kc) {
        const float* ap = &As[mrow * LDA + kc * 32 + quad * 8];
        f32x4 a0 = *(const f32x4*)ap;
        f32x4 a1 = *(const f32x4*)(ap + 4);
        bf16x8 ahi, alo;
#pragma unroll
        for (int j2 = 0; j2 < 4; ++j2) {
            short hi, lo;
            split_bf16(a0[j2], hi, lo);
            ahi[j2] = hi; alo[j2] = lo;
            split_bf16(a1[j2], hi, lo);
            ahi[4 + j2] = hi; alo[4 + j2] = lo;
        }
        bf16x8 bh[8], bl[8];
        size_t boff = ((size_t)kc * 8) * 64 + lane;
#pragma unroll
        for (int nt = 0; nt < 8; ++nt) {
            bh[nt] = BfH[boff + (size_t)nt * 64];
            bl[nt] = BfL[boff + (size_t)nt * 64];
        }
#pragma unroll
        for (int nt = 0; nt < 8; ++nt)
            acc[nt] = __builtin_amdgcn_mfma_f32_16x16x32_bf16(ahi, bh[nt], acc[nt], 0, 0, 0);
#pragma unroll
        for (int nt = 0; nt < 8; ++nt)
            acc[nt] = __builtin_amdgcn_mfma_f32_16x16x32_bf16(alo, bh[nt], acc[nt], 0, 0, 0);
#pragma unroll
        for (int nt = 0; nt < 8; ++nt)
            acc[nt] = __builtin_amdgcn_mfma_f32_16x16x32_bf16(ahi, bl[nt], acc[nt], 0, 0, 0);
    }

    // epilogue: scale row by dinv[m], quantize to bf16 (RNE)
    int mbase = base + w * 16 + quad * 4;
    int ncol = lane & 15;
    float dsc[4];
#pragma unroll
    for (int r = 0; r < 4; ++r)
        dsc[r] = (mbase + r < M) ? dinv[mbase + r] : 0.f;
#pragma unroll
    for (int nt = 0; nt < 8; ++nt) {
#pragma unroll
        for (int r = 0; r < 4; ++r) {
            int m = mbase + r;
            if (m < M) {
                __hip_bfloat16 b = __float2bfloat16(acc[nt][r] * dsc[r]);
                Cb[(size_t)m * HID + nt * 16 + ncol] = __builtin_bit_cast(unsigned short, b);
            }
        }
    }
}

// ---------------- CSR aggregation over bf16 gather buffer ----------------
// out[n] = dinv[n] * (hs[n] + sum_in hs[src]) + bias  (+relu), fp32 accumulate/out
__global__ void k_agg(const unsigned short* __restrict__ hs, const int* __restrict__ row_ptr,
                      const int* __restrict__ csr_src, const float* __restrict__ dinv,
                      const float* __restrict__ bias, float* __restrict__ out, int relu) {
    int n = blockIdx.x;
    int j = threadIdx.x;
    int beg = row_ptr[n];
    int end = row_ptr[n + 1];
    float acc = bf2f(hs[(size_t)n * HID + j]);   // self loop (pre-scaled)
    int k = beg;
    for (; k + 3 < end; k += 4) {
        int s0 = csr_src[k + 0], s1 = csr_src[k + 1];
        int s2 = csr_src[k + 2], s3 = csr_src[k + 3];
        float v0 = bf2f(hs[(size_t)s0 * HID + j]);
        float v1 = bf2f(hs[(size_t)s1 * HID + j]);
        float v2 = bf2f(hs[(size_t)s2 * HID + j]);
        float v3 = bf2f(hs[(size_t)s3 * HID + j]);
        acc += (v0 + v1) + (v2 + v3);
    }
    for (; k < end; ++k)
        acc += bf2f(hs[(size_t)csr_src[k] * HID + j]);
    acc = acc * dinv[n] + bias[j];
    if (relu) acc = fmaxf(acc, 0.f);
    out[(size_t)n * HID + j] = acc;
}

// ---------------- final linear: out = pooled @ Wl + bl ----------------
__global__ void k_final_init(const float* __restrict__ bl, float* __restrict__ out, int total) {
    int t = blockIdx.x * blockDim.x + threadIdx.x;
    if (t < total) out[t] = bl[t & (HID - 1)];
}

#define FR  8      // g-rows per block
#define FKC 800    // K-chunk (6400 / 8)
__global__ void k_final(const float* __restrict__ emb, const float* __restrict__ Wl,
                        float* __restrict__ out, int G) {
    int g0 = blockIdx.x * FR;
    int c  = blockIdx.y;
    int j  = threadIdx.x;
    int k0 = c * FKC;
    const float* pr = emb + (size_t)g0 * (SSUB * HID) + k0;
    float acc[FR] = {};
#pragma unroll 4
    for (int k = 0; k < FKC; ++k) {
        float w = Wl[(size_t)(k0 + k) * HID + j];
#pragma unroll
        for (int r = 0; r < FR; ++r)
            acc[r] += pr[(size_t)r * (SSUB * HID) + k] * w;
    }
#pragma unroll
    for (int r = 0; r < FR; ++r)
        atomicAdd(&out[(size_t)(g0 + r) * HID + j], acc[r]);
}

extern "C" void kernel_launch(void* const* d_in, const int* in_sizes, int n_in,
                              void* d_out, int out_size, void* d_ws, size_t ws_size,
                              hipStream_t stream) {
    const float* x  = (const float*)d_in[0];
    const float* W1 = (const float*)d_in[1];
    const float* b1 = (const float*)d_in[2];
    const float* W2 = (const float*)d_in[3];
    const float* b2 = (const float*)d_in[4];
    const float* Wl = (const float*)d_in[5];
    const float* bl = (const float*)d_in[6];
    const int* edge = (const int*)d_in[7];

    const int N = in_sizes[0] / F_IN;       // 50000
    const int E = in_sizes[7] / 2;          // 1600000
    const int G = N / SSUB;                 // 1000
    const int NH = N * HID;
    const int nblk = (N + 255) / 256;       // 196
    const int slice_size = (N + 7) / 8;     // 6250

    const int* src = edge;
    const int* dst = edge + E;

    // workspace layout
    char* ws = (char*)d_ws;
    float* dinv    = (float*)ws;                 ws += (size_t)N * 4;
    int*   cnt     = (int*)ws;                   ws += (size_t)N * 4;
    int*   row_ptr = (int*)ws;                   ws += (size_t)(N + 64) * 4;
    int*   cursor  = (int*)ws;                   ws += (size_t)N * 4;
    int*   blk_sum = (int*)ws;                   ws += (size_t)(nblk + 64) * 4;
    int*   blk_off = (int*)ws;                   ws += (size_t)(nblk + 64) * 4;
    int*   csr_src = (int*)ws;                   ws += (size_t)E * 4;
    unsigned short* hs0 = (unsigned short*)ws;   ws += (size_t)NH * 2;   // bf16 gather buf L1
    unsigned short* hs1 = (unsigned short*)ws;   ws += (size_t)NH * 2;   // bf16 gather buf L2
    float* h       = (float*)ws;                 ws += (size_t)NH * 4;   // fp32 relu'd hidden
    short* Bf1     = (short*)ws;                 ws += (size_t)2 * F_IN * HID * 2;  // hi+lo bf16
    short* Bf2     = (short*)ws;                 ws += (size_t)2 * HID * HID * 2;

    float* out_final = (float*)d_out;                 // G*H
    float* emb       = out_final + (size_t)G * HID;   // N*H

    // ---- CSR build (also computes dinv) ----
    k_zero_int<<<(N + 255) / 256, 256, 0, stream>>>(cnt, N);
    k_hist<<<(E + 255) / 256, 256, 0, stream>>>(dst, cnt, E);
    k_scan_local<<<nblk, 256, 0, stream>>>(cnt, row_ptr, dinv, blk_sum, N);
    k_scan_blk<<<1, 256, 0, stream>>>(blk_sum, blk_off, nblk);
    k_scan_add<<<nblk, 256, 0, stream>>>(row_ptr, cursor, blk_off, N, nblk);
    {
        int chunks = (E + 255) / 256;
        k_fill_csr<<<chunks * 8, 256, 0, stream>>>(src, dst, cursor, csr_src, E, slice_size);
    }

    // ---- weight splits ----
    k_wsplit<F_IN><<<(F_IN * HID + 255) / 256, 256, 0, stream>>>(W1, Bf1);
    k_wsplit<HID ><<<(HID  * HID + 255) / 256, 256, 0, stream>>>(W2, Bf2);

    // ---- layer 1 ----
    k_gemm_mfma<F_IN><<<(N + 31) / 32, 128, 0, stream>>>(x, Bf1, dinv, hs0, N);  // hs0 = bf16((x@W1)*dinv)
    k_agg<<<N, 128, 0, stream>>>(hs0, row_ptr, csr_src, dinv, b1, h, 1);

    // ---- layer 2 ----
    k_gemm_mfma<HID><<<(N + 31) / 32, 128, 0, stream>>>(h, Bf2, dinv, hs1, N);   // hs1 = bf16((h@W2)*dinv)
    k_agg<<<N, 128, 0, stream>>>(hs1, row_ptr, csr_src, dinv, b2, emb, 0);

    // ---- final linear ----
    k_final_init<<<(G * HID + 255) / 256, 256, 0, stream>>>(bl, out_final, G * HID);
    {
        dim3 grid(G / FR, (SSUB * HID) / FKC);
        k_final<<<grid, 128, 0, stream>>>(emb, Wl, out_final, G);
    }
}

// Round 8
// 520.906 us; speedup vs baseline: 12.0244x; 1.1090x over previous
//
#include <hip/hip_runtime.h>
#include <hip/hip_bf16.h>

#define F_IN 256
#define HID  128
#define SSUB 50
#define KFIN 6400   // SSUB * HID

typedef __attribute__((ext_vector_type(4))) float f32x4;
typedef __attribute__((ext_vector_type(8))) short bf16x8;

__device__ __forceinline__ void split_bf16(float v, short& hi, short& lo) {
    __hip_bfloat16 h = __float2bfloat16(v);
    float hf = __bfloat162float(h);
    __hip_bfloat16 l = __float2bfloat16(v - hf);   // exact residual, then RNE to bf16
    hi = __builtin_bit_cast(short, h);
    lo = __builtin_bit_cast(short, l);
}

__device__ __forceinline__ float bf2f(unsigned short u) {
    return __builtin_bit_cast(float, (unsigned)u << 16);
}

// ---------------- CSR build ----------------

__global__ void k_zero_int(int* __restrict__ p, int n) {
    int i = blockIdx.x * blockDim.x + threadIdx.x;
    if (i < n) p[i] = 0;
}

__global__ void k_hist(const int* __restrict__ dst, int* __restrict__ cnt, int E) {
    int e = blockIdx.x * blockDim.x + threadIdx.x;
    if (e < E) atomicAdd(&cnt[dst[e]], 1);
}

// ---- hierarchical exclusive scan over cnt[0..N) ----
__global__ void k_scan_local(const int* __restrict__ cnt, int* __restrict__ row_ptr,
                             float* __restrict__ dinv, int* __restrict__ blk_sum, int N) {
    __shared__ int buf[256];
    int tid = threadIdx.x;
    int i = blockIdx.x * 256 + tid;
    int v = (i < N) ? cnt[i] : 0;
    buf[tid] = v;
    __syncthreads();
    for (int off = 1; off < 256; off <<= 1) {
        int t = (tid >= off) ? buf[tid - off] : 0;
        __syncthreads();
        buf[tid] += t;
        __syncthreads();
    }
    if (i < N) {
        row_ptr[i] = buf[tid] - v;
        dinv[i] = rsqrtf((float)(v + 1));   // +1 self loop
    }
    if (tid == 255) blk_sum[blockIdx.x] = buf[255];
}

__global__ void k_scan_blk(const int* __restrict__ blk_sum, int* __restrict__ blk_off, int nblk) {
    __shared__ int buf[256];
    int tid = threadIdx.x;
    int v = (tid < nblk) ? blk_sum[tid] : 0;
    buf[tid] = v;
    __syncthreads();
    for (int off = 1; off < 256; off <<= 1) {
        int t = (tid >= off) ? buf[tid - off] : 0;
        __syncthreads();
        buf[tid] += t;
        __syncthreads();
    }
    if (tid < nblk) blk_off[tid] = buf[tid] - v;
    if (tid == 255) blk_off[nblk] = buf[255];
}

__global__ void k_scan_add(int* __restrict__ row_ptr, int* __restrict__ cursor,
                           const int* __restrict__ blk_off, int N, int nblk) {
    int i = blockIdx.x * 256 + threadIdx.x;
    if (i < N) {
        int val = row_ptr[i] + blk_off[blockIdx.x];
        row_ptr[i] = val;
        cursor[i] = val;
    }
    if (i == 0) row_ptr[N] = blk_off[nblk];
}

// XCD-sliced CSR fill (blockIdx%8 -> XCD round-robin; perf heuristic only)
__global__ void k_fill_csr(const int* __restrict__ src, const int* __restrict__ dst,
                           int* __restrict__ cursor, int* __restrict__ csr_src,
                           int E, int slice_size) {
    int slice = blockIdx.x & 7;
    int e = (blockIdx.x >> 3) * 256 + threadIdx.x;
    if (e >= E) return;
    int d = dst[e];
    if (d / slice_size != slice) return;
    int pos = atomicAdd(&cursor[d], 1);
    csr_src[pos] = src[e];
}

// ---------------- W split: fp32 (K x 128) -> fragment-linear bf16 hi/lo ----------------
template<int K>
__global__ void k_wsplit(const float* __restrict__ W, short* __restrict__ Bf) {
    int t = blockIdx.x * 256 + threadIdx.x;
    if (t >= K * HID) return;
    int k = t >> 7, n = t & 127;
    short hi, lo;
    split_bf16(W[t], hi, lo);
    int kc = k >> 5, ko = k & 31;
    int quad = ko >> 3, j = ko & 7;
    int nt = n >> 4, nc = n & 15;
    int lane = (quad << 4) | nc;
    size_t idx = (((size_t)(kc * 8 + nt)) * 64 + lane) * 8 + j;
    Bf[idx] = hi;
    Bf[(size_t)K * HID + idx] = lo;
}

// ---------------- MFMA GEMM: Cb(MxHID, bf16) = (A(MxK, fp32) @ W) * dinv[row] ----------------
template<int K>
__global__ __launch_bounds__(128) void k_gemm_mfma(const float* __restrict__ A,
                                                   const short* __restrict__ Bf,
                                                   const float* __restrict__ dinv,
                                                   unsigned short* __restrict__ Cb, int M) {
    constexpr int LDA = K + 4;
    constexpr int KC = K / 32;
    __shared__ float As[32 * LDA];
    int tid = threadIdx.x;
    int base = blockIdx.x * 32;

    constexpr int ITERS = (32 * (K / 4)) / 128;
#pragma unroll
    for (int i = 0; i < ITERS; ++i) {
        int f4 = tid + i * 128;
        int row = f4 / (K / 4);
        int c4 = f4 % (K / 4);
        f32x4 v = {0.f, 0.f, 0.f, 0.f};
        int m = base + row;
        if (m < M) v = *(const f32x4*)(A + (size_t)m * K + c4 * 4);
        *(f32x4*)(&As[row * LDA + c4 * 4]) = v;
    }
    __syncthreads();

    int lane = tid & 63;
    int w = tid >> 6;
    int quad = lane >> 4;
    int mrow = w * 16 + (lane & 15);
    f32x4 acc[8] = {};
    const bf16x8* BfH = (const bf16x8*)Bf;
    const bf16x8* BfL = (const bf16x8*)(Bf + (size_t)K * HID);

    for (int kc = 0; kc < KC; ++kc) {
        const float* ap = &As[mrow * LDA + kc * 32 + quad * 8];
        f32x4 a0 = *(const f32x4*)ap;
        f32x4 a1 = *(const f32x4*)(ap + 4);
        bf16x8 ahi, alo;
#pragma unroll
        for (int j2 = 0; j2 < 4; ++j2) {
            short hi, lo;
            split_bf16(a0[j2], hi, lo);
            ahi[j2] = hi; alo[j2] = lo;
            split_bf16(a1[j2], hi, lo);
            ahi[4 + j2] = hi; alo[4 + j2] = lo;
        }
        bf16x8 bh[8], bl[8];
        size_t boff = ((size_t)kc * 8) * 64 + lane;
#pragma unroll
        for (int nt = 0; nt < 8; ++nt) {
            bh[nt] = BfH[boff + (size_t)nt * 64];
            bl[nt] = BfL[boff + (size_t)nt * 64];
        }
#pragma unroll
        for (int nt = 0; nt < 8; ++nt)
            acc[nt] = __builtin_amdgcn_mfma_f32_16x16x32_bf16(ahi, bh[nt], acc[nt], 0, 0, 0);
#pragma unroll
        for (int nt = 0; nt < 8; ++nt)
            acc[nt] = __builtin_amdgcn_mfma_f32_16x16x32_bf16(alo, bh[nt], acc[nt], 0, 0, 0);
#pragma unroll
        for (int nt = 0; nt < 8; ++nt)
            acc[nt] = __builtin_amdgcn_mfma_f32_16x16x32_bf16(ahi, bl[nt], acc[nt], 0, 0, 0);
    }

    // epilogue: scale row by dinv[m], quantize to bf16 (RNE)
    int mbase = base + w * 16 + quad * 4;
    int ncol = lane & 15;
    float dsc[4];
#pragma unroll
    for (int r = 0; r < 4; ++r)
        dsc[r] = (mbase + r < M) ? dinv[mbase + r] : 0.f;
#pragma unroll
    for (int nt = 0; nt < 8; ++nt) {
#pragma unroll
        for (int r = 0; r < 4; ++r) {
            int m = mbase + r;
            if (m < M) {
                __hip_bfloat16 b = __float2bfloat16(acc[nt][r] * dsc[r]);
                Cb[(size_t)m * HID + nt * 16 + ncol] = __builtin_bit_cast(unsigned short, b);
            }
        }
    }
}

// ---------------- CSR aggregation over bf16 gather buffer ----------------
// out[n] = dinv[n] * (hs[n] + sum_in hs[src]) + bias  (+relu), fp32 accumulate/out
__global__ void k_agg(const unsigned short* __restrict__ hs, const int* __restrict__ row_ptr,
                      const int* __restrict__ csr_src, const float* __restrict__ dinv,
                      const float* __restrict__ bias, float* __restrict__ out, int relu) {
    int n = blockIdx.x;
    int j = threadIdx.x;
    int beg = row_ptr[n];
    int end = row_ptr[n + 1];
    float acc = bf2f(hs[(size_t)n * HID + j]);   // self loop (pre-scaled)
    int k = beg;
    for (; k + 3 < end; k += 4) {
        int s0 = csr_src[k + 0], s1 = csr_src[k + 1];
        int s2 = csr_src[k + 2], s3 = csr_src[k + 3];
        float v0 = bf2f(hs[(size_t)s0 * HID + j]);
        float v1 = bf2f(hs[(size_t)s1 * HID + j]);
        float v2 = bf2f(hs[(size_t)s2 * HID + j]);
        float v3 = bf2f(hs[(size_t)s3 * HID + j]);
        acc += (v0 + v1) + (v2 + v3);
    }
    for (; k < end; ++k)
        acc += bf2f(hs[(size_t)csr_src[k] * HID + j]);
    acc = acc * dinv[n] + bias[j];
    if (relu) acc = fmaxf(acc, 0.f);
    out[(size_t)n * HID + j] = acc;
}

// ---------------- final linear: out = pooled @ Wl + bl (MFMA, split-K) ----------------
__global__ void k_final_init(const float* __restrict__ bl, float* __restrict__ out, int total) {
    int t = blockIdx.x * blockDim.x + threadIdx.x;
    if (t < total) out[t] = bl[t & (HID - 1)];
}

// block = 128 threads (2 waves), 32 M-rows, K-slice of KS per blockIdx.y,
// LDS tile TILE columns at a time; partials atomically added onto bias-initialized out.
template<int KS, int TILE>
__global__ __launch_bounds__(128) void k_final_mfma(const float* __restrict__ emb,
                                                    const short* __restrict__ Bf,
                                                    float* __restrict__ out, int M) {
    constexpr int LDA = TILE + 4;
    __shared__ float As[32 * LDA];
    int tid = threadIdx.x;
    int g0 = blockIdx.x * 32;
    int k0 = blockIdx.y * KS;
    int lane = tid & 63;
    int w = tid >> 6;
    int quad = lane >> 4;
    int mrow = w * 16 + (lane & 15);
    f32x4 acc[8] = {};
    const bf16x8* BfH = (const bf16x8*)Bf;
    const bf16x8* BfL = (const bf16x8*)(Bf + (size_t)KFIN * HID);

    for (int t = 0; t < KS / TILE; ++t) {
        __syncthreads();
        constexpr int ITERS = (32 * (TILE / 4)) / 128;
#pragma unroll
        for (int i = 0; i < ITERS; ++i) {
            int f4 = tid + i * 128;
            int row = f4 / (TILE / 4);
            int c4 = f4 % (TILE / 4);
            f32x4 v = {0.f, 0.f, 0.f, 0.f};
            int m = g0 + row;
            if (m < M) v = *(const f32x4*)(emb + (size_t)m * KFIN + k0 + t * TILE + c4 * 4);
            *(f32x4*)(&As[row * LDA + c4 * 4]) = v;
        }
        __syncthreads();
        for (int kc = 0; kc < TILE / 32; ++kc) {
            int kcg = (k0 + t * TILE) / 32 + kc;
            const float* ap = &As[mrow * LDA + kc * 32 + quad * 8];
            f32x4 a0 = *(const f32x4*)ap;
            f32x4 a1 = *(const f32x4*)(ap + 4);
            bf16x8 ahi, alo;
#pragma unroll
            for (int j2 = 0; j2 < 4; ++j2) {
                short hi, lo;
                split_bf16(a0[j2], hi, lo);
                ahi[j2] = hi; alo[j2] = lo;
                split_bf16(a1[j2], hi, lo);
                ahi[4 + j2] = hi; alo[4 + j2] = lo;
            }
            bf16x8 bh[8], bl[8];
            size_t boff = (size_t)kcg * 8 * 64 + lane;
#pragma unroll
            for (int nt = 0; nt < 8; ++nt) {
                bh[nt] = BfH[boff + (size_t)nt * 64];
                bl[nt] = BfL[boff + (size_t)nt * 64];
            }
#pragma unroll
            for (int nt = 0; nt < 8; ++nt)
                acc[nt] = __builtin_amdgcn_mfma_f32_16x16x32_bf16(ahi, bh[nt], acc[nt], 0, 0, 0);
#pragma unroll
            for (int nt = 0; nt < 8; ++nt)
                acc[nt] = __builtin_amdgcn_mfma_f32_16x16x32_bf16(alo, bh[nt], acc[nt], 0, 0, 0);
#pragma unroll
            for (int nt = 0; nt < 8; ++nt)
                acc[nt] = __builtin_amdgcn_mfma_f32_16x16x32_bf16(ahi, bl[nt], acc[nt], 0, 0, 0);
        }
    }

    int mbase = g0 + w * 16 + quad * 4;
    int ncol = lane & 15;
#pragma unroll
    for (int nt = 0; nt < 8; ++nt) {
#pragma unroll
        for (int r = 0; r < 4; ++r) {
            int m = mbase + r;
            if (m < M) atomicAdd(&out[(size_t)m * HID + nt * 16 + ncol], acc[nt][r]);
        }
    }
}

extern "C" void kernel_launch(void* const* d_in, const int* in_sizes, int n_in,
                              void* d_out, int out_size, void* d_ws, size_t ws_size,
                              hipStream_t stream) {
    const float* x  = (const float*)d_in[0];
    const float* W1 = (const float*)d_in[1];
    const float* b1 = (const float*)d_in[2];
    const float* W2 = (const float*)d_in[3];
    const float* b2 = (const float*)d_in[4];
    const float* Wl = (const float*)d_in[5];
    const float* bl = (const float*)d_in[6];
    const int* edge = (const int*)d_in[7];

    const int N = in_sizes[0] / F_IN;       // 50000
    const int E = in_sizes[7] / 2;          // 1600000
    const int G = N / SSUB;                 // 1000
    const int NH = N * HID;
    const int nblk = (N + 255) / 256;       // 196
    const int slice_size = (N + 7) / 8;     // 6250

    const int* src = edge;
    const int* dst = edge + E;

    // workspace layout
    char* ws = (char*)d_ws;
    float* dinv    = (float*)ws;                 ws += (size_t)N * 4;
    int*   cnt     = (int*)ws;                   ws += (size_t)N * 4;
    int*   row_ptr = (int*)ws;                   ws += (size_t)(N + 64) * 4;
    int*   cursor  = (int*)ws;                   ws += (size_t)N * 4;
    int*   blk_sum = (int*)ws;                   ws += (size_t)(nblk + 64) * 4;
    int*   blk_off = (int*)ws;                   ws += (size_t)(nblk + 64) * 4;
    int*   csr_src = (int*)ws;                   ws += (size_t)E * 4;
    unsigned short* hs0 = (unsigned short*)ws;   ws += (size_t)NH * 2;   // bf16 gather buf L1
    unsigned short* hs1 = (unsigned short*)ws;   ws += (size_t)NH * 2;   // bf16 gather buf L2
    float* h       = (float*)ws;                 ws += (size_t)NH * 4;   // fp32 relu'd hidden
    short* Bf1     = (short*)ws;                 ws += (size_t)2 * F_IN * HID * 2;  // hi+lo bf16
    short* Bf2     = (short*)ws;                 ws += (size_t)2 * HID * HID * 2;
    short* Bfl     = (short*)ws;                 ws += (size_t)2 * KFIN * HID * 2;

    float* out_final = (float*)d_out;                 // G*H
    float* emb       = out_final + (size_t)G * HID;   // N*H

    // ---- CSR build (also computes dinv) ----
    k_zero_int<<<(N + 255) / 256, 256, 0, stream>>>(cnt, N);
    k_hist<<<(E + 255) / 256, 256, 0, stream>>>(dst, cnt, E);
    k_scan_local<<<nblk, 256, 0, stream>>>(cnt, row_ptr, dinv, blk_sum, N);
    k_scan_blk<<<1, 256, 0, stream>>>(blk_sum, blk_off, nblk);
    k_scan_add<<<nblk, 256, 0, stream>>>(row_ptr, cursor, blk_off, N, nblk);
    {
        int chunks = (E + 255) / 256;
        k_fill_csr<<<chunks * 8, 256, 0, stream>>>(src, dst, cursor, csr_src, E, slice_size);
    }

    // ---- weight splits ----
    k_wsplit<F_IN><<<(F_IN * HID + 255) / 256, 256, 0, stream>>>(W1, Bf1);
    k_wsplit<HID ><<<(HID  * HID + 255) / 256, 256, 0, stream>>>(W2, Bf2);
    k_wsplit<KFIN><<<(KFIN * HID + 255) / 256, 256, 0, stream>>>(Wl, Bfl);

    // ---- layer 1 ----
    k_gemm_mfma<F_IN><<<(N + 31) / 32, 128, 0, stream>>>(x, Bf1, dinv, hs0, N);  // hs0 = bf16((x@W1)*dinv)
    k_agg<<<N, 128, 0, stream>>>(hs0, row_ptr, csr_src, dinv, b1, h, 1);

    // ---- layer 2 ----
    k_gemm_mfma<HID><<<(N + 31) / 32, 128, 0, stream>>>(h, Bf2, dinv, hs1, N);   // hs1 = bf16((h@W2)*dinv)
    k_agg<<<N, 128, 0, stream>>>(hs1, row_ptr, csr_src, dinv, b2, emb, 0);

    // ---- final linear (bias init + MFMA split-K accumulate) ----
    k_final_init<<<(G * HID + 255) / 256, 256, 0, stream>>>(bl, out_final, G * HID);
    {
        dim3 grid((G + 31) / 32, 8);   // 8 K-slices of 800
        k_final_mfma<800, 160><<<grid, 128, 0, stream>>>(emb, Bfl, out_final, G);
    }
}